// Round 12
// baseline (322.535 us; speedup 1.0000x reference)
//
#include <hip/hip_runtime.h>
#include <hip/hip_bf16.h>

typedef __attribute__((ext_vector_type(8))) short bf16x8;
typedef __attribute__((ext_vector_type(4))) float f32x4;
typedef __attribute__((ext_vector_type(4))) unsigned short us4;
typedef __attribute__((ext_vector_type(4))) unsigned int u32x4;

// dims
static constexpr int CC = 128, NN = 16384;       // C, H*W (H=W=128)
static constexpr int O3 = 384;                   // 3*C
static constexpr long long CN  = (long long)CC * NN;   // 2097152
static constexpr long long O3N = (long long)O3 * NN;   // 6291456
// tiled conv layout: [bz][tile=n/64][o][px=n%64], tile block = 384*64 = 24576

__device__ __forceinline__ float wave_sum(float v) {
  for (int o = 32; o; o >>= 1) v += __shfl_xor(v, o);
  return v;
}
__device__ __forceinline__ unsigned pk2bf(float a, float b) {
  __hip_bfloat162 h = __float22bfloat162_rn(make_float2(a, b));
  return *reinterpret_cast<unsigned*>(&h);
}
__device__ __forceinline__ unsigned short f2bf(float f) {
  __hip_bfloat16 h = __float2bfloat16(f);
  return *reinterpret_cast<unsigned short*>(&h);
}
__device__ __forceinline__ float bf2f(unsigned short h) {
  return __uint_as_float((unsigned)h << 16);
}

// ---- prep ----
__global__ __launch_bounds__(64) void k_prep(const float* __restrict__ qkvw,
                                             const float* __restrict__ qkvb,
                                             const float* __restrict__ lnw,
                                             const float* __restrict__ lnb,
                                             const float* __restrict__ projw,
                                             unsigned short* __restrict__ Aq,
                                             unsigned short* __restrict__ Ap,
                                             float* __restrict__ Svec,
                                             float* __restrict__ bias2) {
  int o = blockIdx.x, t = threadIdx.x;
  if (o < O3) {
    float w0 = qkvw[o * 128 + t], w1 = qkvw[o * 128 + t + 64];
    unsigned short h0 = f2bf(w0 * lnw[t]), h1 = f2bf(w1 * lnw[t + 64]);
    Aq[o * 128 + t] = h0; Aq[o * 128 + t + 64] = h1;
    float s = wave_sum(bf2f(h0) + bf2f(h1));
    float bs = wave_sum(w0 * lnb[t] + w1 * lnb[t + 64]);
    if (t == 0) { Svec[o] = s; bias2[o] = qkvb[o] + bs; }
  } else {
    int r = o - O3;
    Ap[r * 128 + t] = f2bf(projw[r * 128 + t]);
    Ap[r * 128 + t + 64] = f2bf(projw[r * 128 + t + 64]);
  }
}

// ---- MFMA qkv GEMM -> TILED output (each block writes one contiguous 16-KB region) ----
__global__ __launch_bounds__(256) void k_qkv_mfma(
    const void* __restrict__ srcp, const float* __restrict__ mu, const float* __restrict__ rs,
    const unsigned short* __restrict__ Aq, const float* __restrict__ Svec,
    const float* __restrict__ bias2, unsigned short* __restrict__ outT,
    int b0, int useg, int srcbf) {
  __shared__ unsigned short As[128 * 136];         // 34.8 KB; reused as out-stage
  __shared__ unsigned short Bs[64 * 136];          // [n][c], stride 136, XOR-swizzled granules
  __shared__ float muL[64], rsL[64];
  int bz = blockIdx.z, bg = b0 + bz;
  int p = blockIdx.x;
  int hi = p / 24, rr0 = p - hi * 24;
  int m0 = (rr0 >> 3) * 128;
  int tile = hi * 8 + (rr0 & 7);
  int n0 = tile * 64;
  int t = threadIdx.x, w = t >> 6, l = t & 63;
  int lr = l & 15, lg = l >> 4;

  // stage A once
  {
    const unsigned short* Asrc = Aq + (size_t)m0 * 128;
#pragma unroll
    for (int r = 0; r < 8; ++r) {
      int v = r * 256 + t;
      int m = v >> 4, c8 = (v & 15) * 8;
      *(u32x4*)&As[m * 136 + c8] = *(const u32x4*)&Asrc[m * 128 + c8];
    }
  }
  // stage B: thread = 4 px x 8 ch; wide loads, pack, swizzled 16B LDS writes
  {
    int pg = t & 15, cbk = t >> 4;
    int c8 = cbk * 8;
    if (!srcbf) {
      const float* xb = (const float*)srcp + (size_t)bg * CN + n0 + pg * 4;
      float4 v[8];
#pragma unroll
      for (int ch = 0; ch < 8; ++ch)
        v[ch] = *(const float4*)&xb[(size_t)(c8 + ch) * NN];
#pragma unroll
      for (int pp = 0; pp < 4; ++pp) {
        unsigned pk[4];
#pragma unroll
        for (int q = 0; q < 4; ++q)
          pk[q] = pk2bf(((const float*)&v[2 * q])[pp], ((const float*)&v[2 * q + 1])[pp]);
        int n = pg * 4 + pp;
        *(u32x4*)&Bs[n * 136 + (c8 ^ ((n & 7) << 3))] = *(const u32x4*)pk;
      }
    } else {
      const unsigned short* xb = (const unsigned short*)srcp + (size_t)bg * CN + n0 + pg * 4;
      us4 v[8];
#pragma unroll
      for (int ch = 0; ch < 8; ++ch)
        v[ch] = *(const us4*)&xb[(size_t)(c8 + ch) * NN];
#pragma unroll
      for (int pp = 0; pp < 4; ++pp) {
        unsigned pk[4];
#pragma unroll
        for (int q = 0; q < 4; ++q)
          pk[q] = (unsigned)v[2 * q][pp] | ((unsigned)v[2 * q + 1][pp] << 16);
        int n = pg * 4 + pp;
        *(u32x4*)&Bs[n * 136 + (c8 ^ ((n & 7) << 3))] = *(const u32x4*)pk;
      }
    }
  }
  __syncthreads();

  // stage-1: in-block LN stats
  if (!useg) {
    int pp = t >> 2, sub = t & 3;
    float s1 = 0.f, s2 = 0.f;
#pragma unroll
    for (int b2 = 0; b2 < 4; ++b2) {
      int c8 = (sub * 4 + b2) * 8;
      int c8s = c8 ^ ((pp & 7) << 3);
      bf16x8 v = *(const bf16x8*)&Bs[pp * 136 + c8s];
#pragma unroll
      for (int q = 0; q < 8; ++q) {
        float f = bf2f((unsigned short)v[q]);
        s1 += f; s2 += f * f;
      }
    }
    s1 += __shfl_xor(s1, 1); s2 += __shfl_xor(s2, 1);
    s1 += __shfl_xor(s1, 2); s2 += __shfl_xor(s2, 2);
    if (sub == 0) {
      float m = s1 * (1.f / 128.f);
      muL[pp] = m;
      rsL[pp] = rsqrtf(s2 * (1.f / 128.f) - m * m + 1e-5f);
    }
  }

  // MFMA
  f32x4 acc[2][4];
#pragma unroll
  for (int i = 0; i < 2; ++i)
#pragma unroll
    for (int j = 0; j < 4; ++j) acc[i][j] = (f32x4){0.f, 0.f, 0.f, 0.f};
#pragma unroll
  for (int ks = 0; ks < 4; ++ks) {
    bf16x8 bfr[4];
#pragma unroll
    for (int j = 0; j < 4; ++j) {
      int row = 16 * j + lr;
      int col = (ks * 32 + lg * 8) ^ ((lr & 7) << 3);
      bfr[j] = *(const bf16x8*)&Bs[row * 136 + col];
    }
#pragma unroll
    for (int i = 0; i < 2; ++i) {
      bf16x8 afr = *(const bf16x8*)&As[(32 * w + 16 * i + lr) * 136 + ks * 32 + lg * 8];
#pragma unroll
      for (int j = 0; j < 4; ++j)
        acc[i][j] = __builtin_amdgcn_mfma_f32_16x16x32_bf16(afr, bfr[j], acc[i][j], 0, 0, 0);
    }
  }
  __syncthreads();

  // epilogue -> LDS stage -> contiguous 16-KB tile store
  float rsv[4], muv[4];
#pragma unroll
  for (int j = 0; j < 4; ++j) {
    int nl = 16 * j + lr;
    if (useg) {
      rsv[j] = rs[(size_t)bg * NN + n0 + nl];
      muv[j] = mu[(size_t)bg * NN + n0 + nl];
    } else {
      rsv[j] = rsL[nl];
      muv[j] = muL[nl];
    }
  }
  unsigned short* Os = As;              // [row 0..127][px 0..63], stride 72
#pragma unroll
  for (int i = 0; i < 2; ++i) {
    int obl = 32 * w + 16 * i + lg * 4;
    float sv[4], bv[4];
#pragma unroll
    for (int r2 = 0; r2 < 4; ++r2) { sv[r2] = Svec[m0 + obl + r2]; bv[r2] = bias2[m0 + obl + r2]; }
#pragma unroll
    for (int j = 0; j < 4; ++j) {
      float rm = rsv[j] * muv[j];
#pragma unroll
      for (int r2 = 0; r2 < 4; ++r2)
        Os[(obl + r2) * 72 + 16 * j + lr] =
            f2bf(fmaf(rsv[j], acc[i][j][r2], bv[r2] - rm * sv[r2]));
    }
  }
  __syncthreads();
  unsigned short* op0 = outT + ((size_t)bz * 256 + tile) * 24576 + (size_t)m0 * 64;
#pragma unroll
  for (int r = 0; r < 4; ++r) {
    int idx = r * 256 + t;
    int row = idx >> 3, ch = idx & 7;
    *(u32x4*)&op0[row * 64 + ch * 8] = *(const u32x4*)&Os[row * 72 + ch * 8];
  }
}

// ---- 3x3 depthwise conv: reads TILED convT, writes PLANAR convP; fused stage-1 reductions ----
__global__ __launch_bounds__(1024) void k_dwc(const unsigned short* __restrict__ convT,
                                              unsigned short* __restrict__ convP,
                                              const float* __restrict__ dww,
                                              const float* __restrict__ dwb,
                                              float* __restrict__ qm,
                                              float* __restrict__ km,
                                              int b0, int stage) {
  __shared__ unsigned short pl[130 * 144];
  __shared__ float red[32 * 128];
  int o = blockIdx.x, bz = blockIdx.y, bg = b0 + bz;
  int t = threadIdx.x;
  unsigned* pl32 = (unsigned*)pl;

  for (int i = t; i < 1168; i += 1024) {
    int idx;
    if (i < 72) idx = i;
    else if (i < 144) idx = 129 * 72 + (i - 72);
    else { int j = i - 144; int row = (j >> 3) + 1; int s = j & 7;
           idx = row * 72 + (s < 4 ? s : 64 + s); }
    pl32[idx] = 0u;
  }
  __syncthreads();
  // load plane from tiled layout: n = row*128 + c8 -> tile = row*2 + (c8>>6), off = c8&63
  {
    const unsigned short* tb = convT + (size_t)bz * O3N + (size_t)o * 64;
#pragma unroll
    for (int r = 0; r < 2; ++r) {
      int idx = r * 1024 + t;
      int row = idx >> 4, c8 = (idx & 15) * 8;
      int tile = (row << 1) | (c8 >> 6), off = c8 & 63;
      *(u32x4*)&pl[(row + 1) * 144 + 8 + c8] = *(const u32x4*)&tb[(size_t)tile * 24576 + off];
    }
  }
  __syncthreads();

  const float* wg = dww + o * 9;
  float w00 = wg[0], w01 = wg[1], w02 = wg[2];
  float w10 = wg[3], w11 = wg[4], w12 = wg[5];
  float w20 = wg[6], w21 = wg[7], w22 = wg[8];
  float bias = dwb[o];
  int mode = (stage == 0) ? (o < 128 ? 1 : (o < 256 ? 2 : 0)) : 0;
  int hh0 = t >> 5, w0 = (t & 31) * 4;
  float csum[4] = {0.f, 0.f, 0.f, 0.f};
  float cmax[4] = {-1e30f, -1e30f, -1e30f, -1e30f};
  unsigned short* base_out = convP + (size_t)bz * O3N + (size_t)o * NN;

#pragma unroll
  for (int g = 0; g < 4; ++g) {
    int h = g * 32 + hh0;
    float a0 = bias, a1 = bias, a2 = bias, a3 = bias;
#pragma unroll
    for (int dr = 0; dr < 3; ++dr) {
      const unsigned short* rp = &pl[(h + dr) * 144];
      us4 cA = *(const us4*)&rp[w0 + 4];
      us4 cB = *(const us4*)&rp[w0 + 8];
      us4 cC = *(const us4*)&rp[w0 + 12];
      float f0 = bf2f(cA[3]), f1 = bf2f(cB[0]), f2 = bf2f(cB[1]);
      float f3 = bf2f(cB[2]), f4 = bf2f(cB[3]), f5 = bf2f(cC[0]);
      float wr0 = (dr == 0) ? w00 : (dr == 1 ? w10 : w20);
      float wr1 = (dr == 0) ? w01 : (dr == 1 ? w11 : w21);
      float wr2 = (dr == 0) ? w02 : (dr == 1 ? w12 : w22);
      a0 += f0 * wr0 + f1 * wr1 + f2 * wr2;
      a1 += f1 * wr0 + f2 * wr1 + f3 * wr2;
      a2 += f2 * wr0 + f3 * wr1 + f4 * wr2;
      a3 += f3 * wr0 + f4 * wr1 + f5 * wr2;
    }
    if (mode == 0) {
      uint2 ov = make_uint2(pk2bf(a0, a1), pk2bf(a2, a3));
      *(uint2*)&base_out[g * 4096 + t * 4] = ov;
    } else if (mode == 1) {
      csum[0] += a0; csum[1] += a1; csum[2] += a2; csum[3] += a3;
    } else {
      cmax[0] = fmaxf(cmax[0], a0); cmax[1] = fmaxf(cmax[1], a1);
      cmax[2] = fmaxf(cmax[2], a2); cmax[3] = fmaxf(cmax[3], a3);
    }
  }

  if (mode) {
    int j = t >> 5;
#pragma unroll
    for (int dx = 0; dx < 4; ++dx)
      red[j * 128 + w0 + dx] = (mode == 1) ? csum[dx] : cmax[dx];
    __syncthreads();
    if (t < 128) {
      float v = red[t];
      if (mode == 1) {
        for (int jj = 1; jj < 32; ++jj) v += red[jj * 128 + t];
        qm[(size_t)bg * NN + o * 128 + t] = v * (1.f / 128.f);
      } else {
        for (int jj = 1; jj < 32; ++jj) v = fmaxf(v, red[jj * 128 + t]);
        km[(size_t)bg * NN + (o - 128) * 128 + t] = v;
      }
    }
  }
}

// ---- stage-2 reductions: mean over channels (planar convP) ----
__global__ __launch_bounds__(256) void k_reduce2(const unsigned short* __restrict__ qkv,
                                                 float* __restrict__ qm, float* __restrict__ km,
                                                 int b0) {
  int bz = blockIdx.y;
  int n = blockIdx.x * 256 + threadIdx.x;
  const unsigned short* base = qkv + (size_t)bz * O3N + n;
  float sq = 0.f, sk = 0.f;
#pragma unroll 4
  for (int c = 0; c < 128; ++c) {
    sq += bf2f(base[(size_t)c * NN]);
    sk += bf2f(base[(size_t)(c + 128) * NN]);
  }
  size_t off = (size_t)(b0 + bz) * NN + n;
  qm[off] = sq * (1.f / 128.f);
  km[off] = sk * (1.f / 128.f);
}

// ---- l2-normalize rows of length 128 in place ----
__global__ void k_norm2(float* __restrict__ qm, float* __restrict__ km, int row0) {
  float* buf = blockIdx.y ? km : qm;
  int r = row0 + blockIdx.x, t = threadIdx.x;   // 64 threads
  float* p = buf + (size_t)r * 128;
  float v0 = p[t], v1 = p[t + 64];
  float s = wave_sum(v0 * v0 + v1 * v1);
  float sc = 1.f / fmaxf(sqrtf(s), 1e-12f);
  p[t] = v0 * sc;
  p[t + 64] = v1 * sc;
}

// ---- attn1 ----
__global__ void k_attn1(const float* __restrict__ qm, const float* __restrict__ km,
                        const float* __restrict__ temp, unsigned short* __restrict__ attnT,
                        int b0) {
  int bg = b0 + blockIdx.y;
  int i = blockIdx.x, t = threadIdx.x;
  const float* qb = qm + (size_t)bg * NN;
  const float* kb = km + (size_t)bg * NN;
  __shared__ float qcol[128];
  __shared__ float wred[2];
  qcol[t] = qb[t * 128 + i];
  __syncthreads();
  float s = 0.f;
#pragma unroll 4
  for (int k = 0; k < 128; ++k) s += qcol[k] * kb[k * 128 + t];
  s *= temp[0];
  int wid = t >> 6, lane = t & 63;
  float mxw = s;
  for (int o = 32; o; o >>= 1) mxw = fmaxf(mxw, __shfl_xor(mxw, o));
  if (lane == 0) wred[wid] = mxw;
  __syncthreads();
  float mx = fmaxf(wred[0], wred[1]);
  float pv = __expf(s - mx);
  __syncthreads();
  float smw = wave_sum(pv);
  if (lane == 0) wred[wid] = smw;
  __syncthreads();
  float denom = wred[0] + wred[1];
  attnT[(size_t)bg * NN + (size_t)t * 128 + i] = f2bf(pv / denom);
}

// ---- attn2 ----
__global__ void k_attn2(const float* __restrict__ qm, const float* __restrict__ km,
                        const float* __restrict__ temp, unsigned short* __restrict__ attnT,
                        int b0) {
  int bg = b0 + blockIdx.y;
  int i = blockIdx.x, t = threadIdx.x;
  const float* qb = qm + (size_t)bg * NN + i * 128;
  const float* kb = km + (size_t)bg * NN + (size_t)t * 128;
  __shared__ float qrow[128];
  __shared__ float wred[2];
  qrow[t] = qb[t];
  __syncthreads();
  float s = 0.f;
#pragma unroll 4
  for (int w = 0; w < 128; ++w) s += qrow[w] * kb[w];
  s *= temp[0];
  int wid = t >> 6, lane = t & 63;
  float mxw = s;
  for (int o = 32; o; o >>= 1) mxw = fmaxf(mxw, __shfl_xor(mxw, o));
  if (lane == 0) wred[wid] = mxw;
  __syncthreads();
  float mx = fmaxf(wred[0], wred[1]);
  float pv = __expf(s - mx);
  __syncthreads();
  float smw = wave_sum(pv);
  if (lane == 0) wred[wid] = smw;
  __syncthreads();
  float denom = wred[0] + wred[1];
  attnT[(size_t)bg * NN + (size_t)t * 128 + i] = f2bf(pv / denom);
}

// ---- FUSED stage-1 apply+proj+stats (reads planar convP v1 rows) ----
__global__ __launch_bounds__(256) void k_ap1(const unsigned short* __restrict__ convP,
                                             const unsigned short* __restrict__ attnT,
                                             const unsigned short* __restrict__ Ap,
                                             const float* __restrict__ pb,
                                             const float* __restrict__ x,
                                             unsigned short* __restrict__ out1,
                                             float* __restrict__ mu, float* __restrict__ rs,
                                             int b0) {
  __shared__ __attribute__((aligned(16))) unsigned short S[32768];   // 64 KB
  unsigned short* TA = S;
  unsigned short* TB = S + 16384;
  int h = blockIdx.x, bz = blockIdx.z, bg = b0 + bz;
  int t = threadIdx.x, wv = t >> 6, l = t & 63, lr = l & 15, lg = l >> 4;

  {
    const unsigned short* vbase = convP + (size_t)bz * O3N + (size_t)256 * NN;
    const unsigned short* abase = attnT + (size_t)bg * NN;
#pragma unroll
    for (int r = 0; r < 8; ++r) {
      int idx = r * 256 + t;
      int row = idx >> 4, c8 = (idx & 15) * 8;
      int c8s = c8 ^ ((row & 7) << 3);
      *(u32x4*)&TA[row * 128 + c8s] = *(const u32x4*)&vbase[((size_t)row * 128 + h) * 128 + c8];
      *(u32x4*)&TB[row * 128 + c8s] = *(const u32x4*)&abase[row * 128 + c8];
    }
  }
  __syncthreads();

  f32x4 acc[2][8];
#pragma unroll
  for (int i = 0; i < 2; ++i)
#pragma unroll
    for (int j = 0; j < 8; ++j) acc[i][j] = (f32x4){0.f, 0.f, 0.f, 0.f};
#pragma unroll
  for (int ks = 0; ks < 4; ++ks) {
    int colx = (ks * 32 + lg * 8) ^ ((lr & 7) << 3);
    bf16x8 bfr[8];
#pragma unroll
    for (int j = 0; j < 8; ++j)
      bfr[j] = *(const bf16x8*)&TB[(16 * j + lr) * 128 + colx];
#pragma unroll
    for (int i = 0; i < 2; ++i) {
      bf16x8 afr = *(const bf16x8*)&TA[(32 * wv + 16 * i + lr) * 128 + colx];
#pragma unroll
      for (int j = 0; j < 8; ++j)
        acc[i][j] = __builtin_amdgcn_mfma_f32_16x16x32_bf16(afr, bfr[j], acc[i][j], 0, 0, 0);
    }
  }
  __syncthreads();

#pragma unroll
  for (int i = 0; i < 2; ++i) {
    int c0 = 32 * wv + 16 * i + lg * 4;
#pragma unroll
    for (int j = 0; j < 8; ++j) {
      int v = 16 * j + lr;
      uint2 ov = make_uint2(pk2bf(acc[i][j][0], acc[i][j][1]),
                            pk2bf(acc[i][j][2], acc[i][j][3]));
      *(uint2*)&TA[v * 128 + (c0 ^ ((v & 7) << 3))] = ov;
    }
  }
#pragma unroll
  for (int r = 0; r < 8; ++r) {
    int idx = r * 256 + t;
    int row = idx >> 4, c8 = (idx & 15) * 8;
    *(u32x4*)&TB[row * 128 + (c8 ^ ((row & 7) << 3))] = *(const u32x4*)&Ap[row * 128 + c8];
  }
  __syncthreads();

#pragma unroll
  for (int i = 0; i < 2; ++i)
#pragma unroll
    for (int j = 0; j < 8; ++j) acc[i][j] = (f32x4){0.f, 0.f, 0.f, 0.f};
#pragma unroll
  for (int ks = 0; ks < 4; ++ks) {
    int colx = (ks * 32 + lg * 8) ^ ((lr & 7) << 3);
    bf16x8 bfr[8];
#pragma unroll
    for (int j = 0; j < 8; ++j)
      bfr[j] = *(const bf16x8*)&TA[(16 * j + lr) * 128 + colx];
#pragma unroll
    for (int i = 0; i < 2; ++i) {
      bf16x8 afr = *(const bf16x8*)&TB[(32 * wv + 16 * i + lr) * 128 + colx];
#pragma unroll
      for (int j = 0; j < 8; ++j)
        acc[i][j] = __builtin_amdgcn_mfma_f32_16x16x32_bf16(afr, bfr[j], acc[i][j], 0, 0, 0);
    }
  }
  __syncthreads();

  unsigned short* Os = S;               // [o][px] stride 136
  float* red1 = (float*)(S + 17408);
  float* red2 = red1 + 128 * 17;
  float s1p[8], s2p[8];
#pragma unroll
  for (int j = 0; j < 8; ++j) { s1p[j] = 0.f; s2p[j] = 0.f; }
#pragma unroll
  for (int i = 0; i < 2; ++i) {
    int o0 = 32 * wv + 16 * i + lg * 4;
    float bv[4];
#pragma unroll
    for (int r2 = 0; r2 < 4; ++r2) bv[r2] = pb[o0 + r2];
#pragma unroll
    for (int j = 0; j < 8; ++j) {
      int n = h * 128 + 16 * j + lr;
#pragma unroll
      for (int r2 = 0; r2 < 4; ++r2) {
        size_t off = (size_t)bg * CN + (size_t)(o0 + r2) * NN + n;
        float val = acc[i][j][r2] + bv[r2] + x[off];
        Os[(o0 + r2) * 136 + 16 * j + lr] = f2bf(val);
        s1p[j] += val;
        s2p[j] += val * val;
      }
    }
  }
#pragma unroll
  for (int j = 0; j < 8; ++j) {
    red1[(16 * j + lr) * 17 + (wv * 4 + lg)] = s1p[j];
    red2[(16 * j + lr) * 17 + (wv * 4 + lg)] = s2p[j];
  }
  __syncthreads();
#pragma unroll
  for (int r = 0; r < 8; ++r) {
    int idx = r * 256 + t;
    int row = idx >> 4, ch = idx & 15;
    unsigned short* op = out1 + (size_t)bg * CN + (size_t)row * NN + h * 128 + ch * 8;
    *(u32x4*)op = *(const u32x4*)&Os[row * 136 + ch * 8];
  }
  if (t < 128) {
    float s1 = 0.f, s2 = 0.f;
#pragma unroll
    for (int kk = 0; kk < 16; ++kk) { s1 += red1[t * 17 + kk]; s2 += red2[t * 17 + kk]; }
    float m = s1 * (1.f / 128.f);
    float var = s2 * (1.f / 128.f) - m * m;
    mu[(size_t)bg * NN + h * 128 + t] = m;
    rs[(size_t)bg * NN + h * 128 + t] = rsqrtf(var + 1e-5f);
  }
}

// ---- apply2 (planar convP in/out) ----
__global__ __launch_bounds__(256) void k_apply2_mfma(unsigned short* __restrict__ convP,
                                                     const unsigned short* __restrict__ attnT,
                                                     int b0) {
  __shared__ unsigned short At[128 * 136];
  __shared__ unsigned short Bt[128 * 136];
  int bz = blockIdx.z, bg = b0 + bz, c = blockIdx.x;
  int t = threadIdx.x, w = t >> 6, l = t & 63, lr = l & 15, lg = l >> 4;
  const unsigned short* vsrc = convP + (size_t)bz * O3N + (size_t)(256 + c) * NN;
  const unsigned short* asrc = attnT + (size_t)bg * NN;
#pragma unroll
  for (int r = 0; r < 8; ++r) {
    int idx = r * 256 + t;
    int row = idx >> 4, c8 = (idx & 15) * 8;
    *(u32x4*)&At[row * 136 + c8] = *(const u32x4*)&asrc[row * 128 + c8];
    us4 lo = *(const us4*)&vsrc[row * 128 + c8];
    us4 hi = *(const us4*)&vsrc[row * 128 + c8 + 4];
#pragma unroll
    for (int q = 0; q < 4; ++q) {
      Bt[(c8 + q) * 136 + row] = lo[q];
      Bt[(c8 + 4 + q) * 136 + row] = hi[q];
    }
  }
  __syncthreads();
  f32x4 acc[2][8];
#pragma unroll
  for (int i = 0; i < 2; ++i)
#pragma unroll
    for (int j = 0; j < 8; ++j) acc[i][j] = (f32x4){0.f, 0.f, 0.f, 0.f};
#pragma unroll
  for (int ks = 0; ks < 4; ++ks) {
    bf16x8 bfr[8];
#pragma unroll
    for (int j = 0; j < 8; ++j)
      bfr[j] = *(const bf16x8*)&Bt[(16 * j + lr) * 136 + ks * 32 + lg * 8];
#pragma unroll
    for (int i = 0; i < 2; ++i) {
      bf16x8 afr = *(const bf16x8*)&At[(32 * w + 16 * i + lr) * 136 + ks * 32 + lg * 8];
#pragma unroll
      for (int j = 0; j < 8; ++j)
        acc[i][j] = __builtin_amdgcn_mfma_f32_16x16x32_bf16(afr, bfr[j], acc[i][j], 0, 0, 0);
    }
  }
  __syncthreads();
  unsigned short* Os = At;
#pragma unroll
  for (int i = 0; i < 2; ++i)
#pragma unroll
    for (int j = 0; j < 8; ++j) {
      int g = 32 * w + 16 * i + lg * 4;
      Os[g * 136 + 16 * j + lr] = f2bf(acc[i][j][0]);
      Os[(g + 1) * 136 + 16 * j + lr] = f2bf(acc[i][j][1]);
      Os[(g + 2) * 136 + 16 * j + lr] = f2bf(acc[i][j][2]);
      Os[(g + 3) * 136 + 16 * j + lr] = f2bf(acc[i][j][3]);
    }
  __syncthreads();
  unsigned short* ob = convP + (size_t)bz * O3N + (size_t)c * NN;  // q-region plane c
#pragma unroll
  for (int r = 0; r < 8; ++r) {
    int idx = r * 256 + t;
    int row = idx >> 4, ch = idx & 15;
    *(u32x4*)&ob[(size_t)row * 128 + ch * 8] = *(const u32x4*)&Os[row * 136 + ch * 8];
  }
}

// ---- proj (planar tmp in, bf16 res, fp32 dst) ----
__global__ __launch_bounds__(256) void k_proj_mfma(
    const unsigned short* __restrict__ tin, const unsigned short* __restrict__ Ap,
    const float* __restrict__ pb, const unsigned short* __restrict__ res,
    float* __restrict__ dst, int b0) {
  __shared__ unsigned short Al[128 * 136];
  __shared__ unsigned short Bs2[64 * 136];
  int bz = blockIdx.z, bg = b0 + bz;
  int n0 = blockIdx.x * 64;
  int t = threadIdx.x, w = t >> 6, l = t & 63, lr = l & 15, lg = l >> 4;

#pragma unroll
  for (int r = 0; r < 8; ++r) {
    int v = r * 256 + t;
    int m = v >> 4, c8 = (v & 15) * 8;
    *(u32x4*)&Al[m * 136 + c8] = *(const u32x4*)&Ap[m * 128 + c8];
  }
  {
    int pg = t & 15, cbk = t >> 4;
    int c8 = cbk * 8;
    const unsigned short* tb = tin + (size_t)bz * O3N + n0 + pg * 4;
    us4 v[8];
#pragma unroll
    for (int ch = 0; ch < 8; ++ch)
      v[ch] = *(const us4*)&tb[(size_t)(c8 + ch) * NN];
#pragma unroll
    for (int pp = 0; pp < 4; ++pp) {
      unsigned pk[4];
#pragma unroll
      for (int q = 0; q < 4; ++q)
        pk[q] = (unsigned)v[2 * q][pp] | ((unsigned)v[2 * q + 1][pp] << 16);
      int n = pg * 4 + pp;
      *(u32x4*)&Bs2[n * 136 + (c8 ^ ((n & 7) << 3))] = *(const u32x4*)pk;
    }
  }
  __syncthreads();

  f32x4 acc[2][4];
#pragma unroll
  for (int i = 0; i < 2; ++i)
#pragma unroll
    for (int j = 0; j < 4; ++j) acc[i][j] = (f32x4){0.f, 0.f, 0.f, 0.f};

#pragma unroll
  for (int ks = 0; ks < 4; ++ks) {
    bf16x8 bfr[4];
#pragma unroll
    for (int j = 0; j < 4; ++j) {
      int row = 16 * j + lr;
      int col = (ks * 32 + lg * 8) ^ ((lr & 7) << 3);
      bfr[j] = *(const bf16x8*)&Bs2[row * 136 + col];
    }
#pragma unroll
    for (int i = 0; i < 2; ++i) {
      bf16x8 afr = *(const bf16x8*)&Al[(32 * w + 16 * i + lr) * 136 + ks * 32 + lg * 8];
#pragma unroll
      for (int j = 0; j < 4; ++j)
        acc[i][j] = __builtin_amdgcn_mfma_f32_16x16x32_bf16(afr, bfr[j], acc[i][j], 0, 0, 0);
    }
  }

#pragma unroll
  for (int i = 0; i < 2; ++i) {
    int ob = 32 * w + 16 * i + lg * 4;
    float bv[4];
#pragma unroll
    for (int r2 = 0; r2 < 4; ++r2) bv[r2] = pb[ob + r2];
#pragma unroll
    for (int j = 0; j < 4; ++j) {
      int n = n0 + 16 * j + lr;
#pragma unroll
      for (int r2 = 0; r2 < 4; ++r2) {
        size_t off = (size_t)bg * CN + (size_t)(ob + r2) * NN + n;
        dst[off] = acc[i][j][r2] + bv[r2] + bf2f(res[off]);
      }
    }
  }
}

extern "C" void kernel_launch(void* const* d_in, const int* in_sizes, int n_in,
                              void* d_out, int out_size, void* d_ws, size_t ws_size,
                              hipStream_t stream) {
  (void)in_sizes; (void)n_in; (void)out_size;
  const float* x     = (const float*)d_in[0];
  const float* lnw   = (const float*)d_in[1];
  const float* lnb   = (const float*)d_in[2];
  const float* qkvw  = (const float*)d_in[3];
  const float* qkvb  = (const float*)d_in[4];
  const float* dww   = (const float*)d_in[5];
  const float* dwb   = (const float*)d_in[6];
  const float* projw = (const float*)d_in[7];
  const float* projb = (const float*)d_in[8];
  const float* temp1 = (const float*)d_in[9];
  const float* temp2 = (const float*)d_in[10];
  float* out = (float*)d_out;

  // bytes: convT + convP (nb*O3N bf16 each) + out1 (8*CN bf16) + floats + attnT + consts
  auto needBytes = [&](size_t nb) {
    return (2 * nb * (size_t)O3N + 8ull * CN + 8ull * NN + 49152 + 16384) * 2 +
           (4ull * 131072 + 768) * 4;
  };
  size_t NB = 8;
  while (NB > 1 && ws_size < needBytes(NB)) NB >>= 1;
  if (ws_size < needBytes(1)) return;

  unsigned short* convT = (unsigned short*)d_ws;
  unsigned short* convP = convT + NB * (size_t)O3N;
  unsigned short* out1  = convP + NB * (size_t)O3N;
  float* mu = (float*)(out1 + 8ull * CN);
  float* rs = mu + 131072;
  float* qm = rs + 131072;
  float* km = qm + 131072;
  unsigned short* attnT = (unsigned short*)(km + 131072);
  float* Svec  = (float*)(attnT + 8ull * NN);
  float* bias2 = Svec + 384;
  unsigned short* Aq = (unsigned short*)(bias2 + 384);
  unsigned short* Ap = Aq + 49152;

  k_prep<<<512, 64, 0, stream>>>(qkvw, qkvb, lnw, lnb, projw, Aq, Ap, Svec, bias2);

  // ---- stage 1 ----
  for (int b0 = 0; b0 < 8; b0 += (int)NB) {
    k_qkv_mfma<<<dim3(768, 1, NB), 256, 0, stream>>>(x, mu, rs, Aq, Svec, bias2, convT,
                                                     b0, 0, 0);
    k_dwc<<<dim3(384, NB), 1024, 0, stream>>>(convT, convP, dww, dwb, qm, km, b0, 0);
    k_norm2<<<dim3(NB * 128, 2), 64, 0, stream>>>(qm, km, b0 * 128);
    k_attn1<<<dim3(128, NB), 128, 0, stream>>>(qm, km, temp1, attnT, b0);
    k_ap1<<<dim3(128, 1, NB), 256, 0, stream>>>(convP, attnT, Ap, projb, x, out1, mu, rs, b0);
  }
  // ---- stage 2 ----
  for (int b0 = 0; b0 < 8; b0 += (int)NB) {
    k_qkv_mfma<<<dim3(768, 1, NB), 256, 0, stream>>>(out1, mu, rs, Aq, Svec, bias2, convT,
                                                     b0, 1, 1);
    k_dwc<<<dim3(384, NB), 1024, 0, stream>>>(convT, convP, dww, dwb, qm, km, b0, 1);
    k_reduce2<<<dim3(64, NB), 256, 0, stream>>>(convP, qm, km, b0);
    k_norm2<<<dim3(NB * 128, 2), 64, 0, stream>>>(qm, km, b0 * 128);
    k_attn2<<<dim3(128, NB), 128, 0, stream>>>(qm, km, temp2, attnT, b0);
    k_apply2_mfma<<<dim3(128, 1, NB), 256, 0, stream>>>(convP, attnT, b0);
    k_proj_mfma<<<dim3(256, 1, NB), 256, 0, stream>>>(convP, Ap, projb, out1, out, b0);
  }
}

// Round 13
// 305.213 us; speedup vs baseline: 1.0568x; 1.0568x over previous
//
#include <hip/hip_runtime.h>
#include <hip/hip_bf16.h>

typedef __attribute__((ext_vector_type(8))) short bf16x8;
typedef __attribute__((ext_vector_type(4))) float f32x4;
typedef __attribute__((ext_vector_type(4))) unsigned short us4;
typedef __attribute__((ext_vector_type(4))) unsigned int u32x4;

// dims
static constexpr int CC = 128, NN = 16384;       // C, H*W (H=W=128)
static constexpr int O3 = 384;                   // 3*C
static constexpr long long CN  = (long long)CC * NN;   // 2097152
static constexpr long long O3N = (long long)O3 * NN;   // 6291456

__device__ __forceinline__ float wave_sum(float v) {
  for (int o = 32; o; o >>= 1) v += __shfl_xor(v, o);
  return v;
}
__device__ __forceinline__ unsigned pk2bf(float a, float b) {
  __hip_bfloat162 h = __float22bfloat162_rn(make_float2(a, b));
  return *reinterpret_cast<unsigned*>(&h);
}
__device__ __forceinline__ unsigned short f2bf(float f) {
  __hip_bfloat16 h = __float2bfloat16(f);
  return *reinterpret_cast<unsigned short*>(&h);
}
__device__ __forceinline__ float bf2f(unsigned short h) {
  return __uint_as_float((unsigned)h << 16);
}

// ---- prep: A' = bf16(W*lnw), S[o] = sum(A'), bias2[o] = bq + sum(W*lnb); proj W -> bf16 ----
__global__ __launch_bounds__(64) void k_prep(const float* __restrict__ qkvw,
                                             const float* __restrict__ qkvb,
                                             const float* __restrict__ lnw,
                                             const float* __restrict__ lnb,
                                             const float* __restrict__ projw,
                                             unsigned short* __restrict__ Aq,
                                             unsigned short* __restrict__ Ap,
                                             float* __restrict__ Svec,
                                             float* __restrict__ bias2) {
  int o = blockIdx.x, t = threadIdx.x;
  if (o < O3) {
    float w0 = qkvw[o * 128 + t], w1 = qkvw[o * 128 + t + 64];
    unsigned short h0 = f2bf(w0 * lnw[t]), h1 = f2bf(w1 * lnw[t + 64]);
    Aq[o * 128 + t] = h0; Aq[o * 128 + t + 64] = h1;
    float s = wave_sum(bf2f(h0) + bf2f(h1));
    float bs = wave_sum(w0 * lnb[t] + w1 * lnb[t + 64]);
    if (t == 0) { Svec[o] = s; bias2[o] = qkvb[o] + bs; }
  } else {
    int r = o - O3;
    Ap[r * 128 + t] = f2bf(projw[r * 128 + t]);
    Ap[r * 128 + t + 64] = f2bf(projw[r * 128 + t + 64]);
  }
}

// ---- MFMA qkv GEMM (R4 structure: full M=384 per block, A staged per-k-step). ----
// out[bz,o,n] = bf16( rs[n]*acc + (bias2[o] - rs[n]*mu[n]*S[o]) ); bf16 out scattered.
__global__ __launch_bounds__(256) void k_qkv_mfma(
    const void* __restrict__ srcp, const float* __restrict__ mu, const float* __restrict__ rs,
    const unsigned short* __restrict__ Aq, const float* __restrict__ Svec,
    const float* __restrict__ bias2, unsigned short* __restrict__ out,
    int b0, int useg, int srcbf) {
  __shared__ unsigned short Bs[64 * 128];          // [n][c], XOR-swizzled 8-ch granules
  __shared__ unsigned short As[384 * 40];          // [o][cc] per k-step
  __shared__ float muL[64], rsL[64];
  int bz = blockIdx.z, bg = b0 + bz;
  int n0 = blockIdx.x * 64;
  int t = threadIdx.x, w = t >> 6, l = t & 63;
  int lr = l & 15, lg = l >> 4;

  // stage B: thread = 4 px x 8 ch; wide loads, hw pack, swizzled 16B LDS writes
  {
    int pg = t & 15, cbk = t >> 4;
    int c8 = cbk * 8;
    if (!srcbf) {
      const float* xb = (const float*)srcp + (size_t)bg * CN + n0 + pg * 4;
      float4 v[8];
#pragma unroll
      for (int ch = 0; ch < 8; ++ch)
        v[ch] = *(const float4*)&xb[(size_t)(c8 + ch) * NN];
#pragma unroll
      for (int pp = 0; pp < 4; ++pp) {
        unsigned pk[4];
#pragma unroll
        for (int q = 0; q < 4; ++q)
          pk[q] = pk2bf(((const float*)&v[2 * q])[pp], ((const float*)&v[2 * q + 1])[pp]);
        int n = pg * 4 + pp;
        *(u32x4*)&Bs[n * 128 + (c8 ^ ((n & 7) << 3))] = *(const u32x4*)pk;
      }
    } else {
      const unsigned short* xb = (const unsigned short*)srcp + (size_t)bg * CN + n0 + pg * 4;
      us4 v[8];
#pragma unroll
      for (int ch = 0; ch < 8; ++ch)
        v[ch] = *(const us4*)&xb[(size_t)(c8 + ch) * NN];
#pragma unroll
      for (int pp = 0; pp < 4; ++pp) {
        unsigned pk[4];
#pragma unroll
        for (int q = 0; q < 4; ++q)
          pk[q] = (unsigned)v[2 * q][pp] | ((unsigned)v[2 * q + 1][pp] << 16);
        int n = pg * 4 + pp;
        *(u32x4*)&Bs[n * 128 + (c8 ^ ((n & 7) << 3))] = *(const u32x4*)pk;
      }
    }
  }
  __syncthreads();

  // stage-1: in-block LN stats from the bf16 tile (4 threads per pixel)
  if (!useg) {
    int pp = t >> 2, sub = t & 3;
    float s1 = 0.f, s2 = 0.f;
#pragma unroll
    for (int b2 = 0; b2 < 4; ++b2) {
      int c8 = (sub * 4 + b2) * 8;
      int c8s = c8 ^ ((pp & 7) << 3);
      bf16x8 v = *(const bf16x8*)&Bs[pp * 128 + c8s];
#pragma unroll
      for (int q = 0; q < 8; ++q) {
        float f = bf2f((unsigned short)v[q]);
        s1 += f; s2 += f * f;
      }
    }
    s1 += __shfl_xor(s1, 1); s2 += __shfl_xor(s2, 1);
    s1 += __shfl_xor(s1, 2); s2 += __shfl_xor(s2, 2);
    if (sub == 0) {
      float m = s1 * (1.f / 128.f);
      muL[pp] = m;
      rsL[pp] = rsqrtf(s2 * (1.f / 128.f) - m * m + 1e-5f);
    }
  }

  // MFMA over full M=384: A staged per k-step (R4 pattern)
  f32x4 acc[6][4];
#pragma unroll
  for (int i = 0; i < 6; ++i)
#pragma unroll
    for (int j = 0; j < 4; ++j) acc[i][j] = (f32x4){0.f, 0.f, 0.f, 0.f};

  const unsigned int* Asrc = (const unsigned int*)Aq;
  unsigned int* Adst = (unsigned int*)As;
  for (int ks = 0; ks < 4; ++ks) {
    __syncthreads();                     // B/stats done (ks=0) / prior As reads done
#pragma unroll
    for (int r = 0; r < 24; ++r) {       // stage A: 384 x 32 bf16 = 6144 u32
      int idx = r * 256 + t;
      int o = idx >> 4, cp = idx & 15;
      Adst[o * 20 + cp] = Asrc[(size_t)o * 64 + ks * 16 + cp];
    }
    __syncthreads();
    bf16x8 bfr[4];
#pragma unroll
    for (int j = 0; j < 4; ++j) {
      int row = 16 * j + lr;
      int col = (ks * 32 + lg * 8) ^ ((lr & 7) << 3);
      bfr[j] = *(const bf16x8*)&Bs[row * 128 + col];
    }
#pragma unroll
    for (int i = 0; i < 6; ++i) {
      bf16x8 afr = *(const bf16x8*)&As[(96 * w + 16 * i + lr) * 40 + lg * 8];
#pragma unroll
      for (int j = 0; j < 4; ++j)
        acc[i][j] = __builtin_amdgcn_mfma_f32_16x16x32_bf16(afr, bfr[j], acc[i][j], 0, 0, 0);
    }
  }

  // epilogue (fused FMA form)
  float rsv[4], muv[4];
#pragma unroll
  for (int j = 0; j < 4; ++j) {
    int nl = 16 * j + lr;
    if (useg) {
      rsv[j] = rs[(size_t)bg * NN + n0 + nl];
      muv[j] = mu[(size_t)bg * NN + n0 + nl];
    } else {
      rsv[j] = rsL[nl];
      muv[j] = muL[nl];
    }
  }
#pragma unroll
  for (int i = 0; i < 6; ++i) {
    int ob = 96 * w + 16 * i + lg * 4;
    float sv[4], bv[4];
#pragma unroll
    for (int r2 = 0; r2 < 4; ++r2) { sv[r2] = Svec[ob + r2]; bv[r2] = bias2[ob + r2]; }
#pragma unroll
    for (int j = 0; j < 4; ++j) {
      int n = n0 + 16 * j + lr;
      float rm = rsv[j] * muv[j];
      unsigned short* op = out + (size_t)bz * O3N + n;
#pragma unroll
      for (int r2 = 0; r2 < 4; ++r2)
        op[(size_t)(ob + r2) * NN] = f2bf(fmaf(rsv[j], acc[i][j][r2], bv[r2] - rm * sv[r2]));
    }
  }
}

// ---- 3x3 depthwise conv, bf16 in/out IN PLACE, padded-LDS, fused stage-1 reductions ----
__global__ __launch_bounds__(1024) void k_dwc(unsigned short* __restrict__ buf,
                                              const float* __restrict__ dww,
                                              const float* __restrict__ dwb,
                                              float* __restrict__ qm,
                                              float* __restrict__ km,
                                              int b0, int stage) {
  __shared__ unsigned short pl[130 * 144];
  __shared__ float red[32 * 128];
  int o = blockIdx.x, bz = blockIdx.y, bg = b0 + bz;
  int t = threadIdx.x;
  unsigned short* base = buf + (size_t)bz * O3N + (size_t)o * NN;
  unsigned* pl32 = (unsigned*)pl;

  for (int i = t; i < 1168; i += 1024) {
    int idx;
    if (i < 72) idx = i;
    else if (i < 144) idx = 129 * 72 + (i - 72);
    else { int j = i - 144; int row = (j >> 3) + 1; int s = j & 7;
           idx = row * 72 + (s < 4 ? s : 64 + s); }
    pl32[idx] = 0u;
  }
  __syncthreads();
#pragma unroll
  for (int r = 0; r < 2; ++r) {
    int idx = r * 1024 + t;
    int row = idx >> 4, c8 = (idx & 15) * 8;
    *(u32x4*)&pl[(row + 1) * 144 + 8 + c8] = *(const u32x4*)&base[row * 128 + c8];
  }
  __syncthreads();

  const float* wg = dww + o * 9;
  float w00 = wg[0], w01 = wg[1], w02 = wg[2];
  float w10 = wg[3], w11 = wg[4], w12 = wg[5];
  float w20 = wg[6], w21 = wg[7], w22 = wg[8];
  float bias = dwb[o];
  int mode = (stage == 0) ? (o < 128 ? 1 : (o < 256 ? 2 : 0)) : 0;
  int hh0 = t >> 5, w0 = (t & 31) * 4;
  float csum[4] = {0.f, 0.f, 0.f, 0.f};
  float cmax[4] = {-1e30f, -1e30f, -1e30f, -1e30f};

#pragma unroll
  for (int g = 0; g < 4; ++g) {
    int h = g * 32 + hh0;
    float a0 = bias, a1 = bias, a2 = bias, a3 = bias;
#pragma unroll
    for (int dr = 0; dr < 3; ++dr) {
      const unsigned short* rp = &pl[(h + dr) * 144];
      us4 cA = *(const us4*)&rp[w0 + 4];
      us4 cB = *(const us4*)&rp[w0 + 8];
      us4 cC = *(const us4*)&rp[w0 + 12];
      float f0 = bf2f(cA[3]), f1 = bf2f(cB[0]), f2 = bf2f(cB[1]);
      float f3 = bf2f(cB[2]), f4 = bf2f(cB[3]), f5 = bf2f(cC[0]);
      float wr0 = (dr == 0) ? w00 : (dr == 1 ? w10 : w20);
      float wr1 = (dr == 0) ? w01 : (dr == 1 ? w11 : w21);
      float wr2 = (dr == 0) ? w02 : (dr == 1 ? w12 : w22);
      a0 += f0 * wr0 + f1 * wr1 + f2 * wr2;
      a1 += f1 * wr0 + f2 * wr1 + f3 * wr2;
      a2 += f2 * wr0 + f3 * wr1 + f4 * wr2;
      a3 += f3 * wr0 + f4 * wr1 + f5 * wr2;
    }
    if (mode == 0) {
      uint2 ov = make_uint2(pk2bf(a0, a1), pk2bf(a2, a3));
      *(uint2*)&base[g * 4096 + t * 4] = ov;
    } else if (mode == 1) {
      csum[0] += a0; csum[1] += a1; csum[2] += a2; csum[3] += a3;
    } else {
      cmax[0] = fmaxf(cmax[0], a0); cmax[1] = fmaxf(cmax[1], a1);
      cmax[2] = fmaxf(cmax[2], a2); cmax[3] = fmaxf(cmax[3], a3);
    }
  }

  if (mode) {
    int j = t >> 5;
#pragma unroll
    for (int dx = 0; dx < 4; ++dx)
      red[j * 128 + w0 + dx] = (mode == 1) ? csum[dx] : cmax[dx];
    __syncthreads();
    if (t < 128) {
      float v = red[t];
      if (mode == 1) {
        for (int jj = 1; jj < 32; ++jj) v += red[jj * 128 + t];
        qm[(size_t)bg * NN + o * 128 + t] = v * (1.f / 128.f);
      } else {
        for (int jj = 1; jj < 32; ++jj) v = fmaxf(v, red[jj * 128 + t]);
        km[(size_t)bg * NN + (o - 128) * 128 + t] = v;
      }
    }
  }
}

// ---- stage-2 reductions: mean over channels of bf16 q,k planes -> [b, h, w] ----
__global__ __launch_bounds__(256) void k_reduce2(const unsigned short* __restrict__ qkv,
                                                 float* __restrict__ qm, float* __restrict__ km,
                                                 int b0) {
  int bz = blockIdx.y;
  int n = blockIdx.x * 256 + threadIdx.x;
  const unsigned short* base = qkv + (size_t)bz * O3N + n;
  float sq = 0.f, sk = 0.f;
#pragma unroll 4
  for (int c = 0; c < 128; ++c) {
    sq += bf2f(base[(size_t)c * NN]);
    sk += bf2f(base[(size_t)(c + 128) * NN]);
  }
  size_t off = (size_t)(b0 + bz) * NN + n;
  qm[off] = sq * (1.f / 128.f);
  km[off] = sk * (1.f / 128.f);
}

// ---- l2-normalize rows of length 128 in place ----
__global__ void k_norm2(float* __restrict__ qm, float* __restrict__ km, int row0) {
  float* buf = blockIdx.y ? km : qm;
  int r = row0 + blockIdx.x, t = threadIdx.x;   // 64 threads
  float* p = buf + (size_t)r * 128;
  float v0 = p[t], v1 = p[t + 64];
  float s = wave_sum(v0 * v0 + v1 * v1);
  float sc = 1.f / fmaxf(sqrtf(s), 1e-12f);
  p[t] = v0 * sc;
  p[t + 64] = v1 * sc;
}

// ---- attn1: scores over c; writes attnT[v][w] bf16 ----
__global__ void k_attn1(const float* __restrict__ qm, const float* __restrict__ km,
                        const float* __restrict__ temp, unsigned short* __restrict__ attnT,
                        int b0) {
  int bg = b0 + blockIdx.y;
  int i = blockIdx.x, t = threadIdx.x;
  const float* qb = qm + (size_t)bg * NN;
  const float* kb = km + (size_t)bg * NN;
  __shared__ float qcol[128];
  __shared__ float wred[2];
  qcol[t] = qb[t * 128 + i];
  __syncthreads();
  float s = 0.f;
#pragma unroll 4
  for (int k = 0; k < 128; ++k) s += qcol[k] * kb[k * 128 + t];
  s *= temp[0];
  int wid = t >> 6, lane = t & 63;
  float mxw = s;
  for (int o = 32; o; o >>= 1) mxw = fmaxf(mxw, __shfl_xor(mxw, o));
  if (lane == 0) wred[wid] = mxw;
  __syncthreads();
  float mx = fmaxf(wred[0], wred[1]);
  float pv = __expf(s - mx);
  __syncthreads();
  float smw = wave_sum(pv);
  if (lane == 0) wred[wid] = smw;
  __syncthreads();
  float denom = wred[0] + wred[1];
  attnT[(size_t)bg * NN + (size_t)t * 128 + i] = f2bf(pv / denom);
}

// ---- attn2: scores over w; writes attnT[g][h] bf16 ----
__global__ void k_attn2(const float* __restrict__ qm, const float* __restrict__ km,
                        const float* __restrict__ temp, unsigned short* __restrict__ attnT,
                        int b0) {
  int bg = b0 + blockIdx.y;
  int i = blockIdx.x, t = threadIdx.x;
  const float* qb = qm + (size_t)bg * NN + i * 128;
  const float* kb = km + (size_t)bg * NN + (size_t)t * 128;
  __shared__ float qrow[128];
  __shared__ float wred[2];
  qrow[t] = qb[t];
  __syncthreads();
  float s = 0.f;
#pragma unroll 4
  for (int w = 0; w < 128; ++w) s += qrow[w] * kb[w];
  s *= temp[0];
  int wid = t >> 6, lane = t & 63;
  float mxw = s;
  for (int o = 32; o; o >>= 1) mxw = fmaxf(mxw, __shfl_xor(mxw, o));
  if (lane == 0) wred[wid] = mxw;
  __syncthreads();
  float mx = fmaxf(wred[0], wred[1]);
  float pv = __expf(s - mx);
  __syncthreads();
  float smw = wave_sum(pv);
  if (lane == 0) wred[wid] = smw;
  __syncthreads();
  float denom = wred[0] + wred[1];
  attnT[(size_t)bg * NN + (size_t)t * 128 + i] = f2bf(pv / denom);
}

// ---- FUSED stage-1 apply+proj+stats: one block per h-row; dense LDS-staged out1 store. ----
__global__ __launch_bounds__(256) void k_ap1(const unsigned short* __restrict__ buf,
                                             const unsigned short* __restrict__ attnT,
                                             const unsigned short* __restrict__ Ap,
                                             const float* __restrict__ pb,
                                             const float* __restrict__ x,
                                             unsigned short* __restrict__ out1,
                                             float* __restrict__ mu, float* __restrict__ rs,
                                             int b0) {
  __shared__ __attribute__((aligned(16))) unsigned short S[32768];   // 64 KB
  unsigned short* TA = S;
  unsigned short* TB = S + 16384;
  int h = blockIdx.x, bz = blockIdx.z, bg = b0 + bz;
  int t = threadIdx.x, wv = t >> 6, l = t & 63, lr = l & 15, lg = l >> 4;

  {
    const unsigned short* vbase = buf + (size_t)bz * O3N + (size_t)256 * NN;
    const unsigned short* abase = attnT + (size_t)bg * NN;
#pragma unroll
    for (int r = 0; r < 8; ++r) {
      int idx = r * 256 + t;
      int row = idx >> 4, c8 = (idx & 15) * 8;
      int c8s = c8 ^ ((row & 7) << 3);
      *(u32x4*)&TA[row * 128 + c8s] = *(const u32x4*)&vbase[((size_t)row * 128 + h) * 128 + c8];
      *(u32x4*)&TB[row * 128 + c8s] = *(const u32x4*)&abase[row * 128 + c8];
    }
  }
  __syncthreads();

  f32x4 acc[2][8];
#pragma unroll
  for (int i = 0; i < 2; ++i)
#pragma unroll
    for (int j = 0; j < 8; ++j) acc[i][j] = (f32x4){0.f, 0.f, 0.f, 0.f};
#pragma unroll
  for (int ks = 0; ks < 4; ++ks) {
    int colx = (ks * 32 + lg * 8) ^ ((lr & 7) << 3);
    bf16x8 bfr[8];
#pragma unroll
    for (int j = 0; j < 8; ++j)
      bfr[j] = *(const bf16x8*)&TB[(16 * j + lr) * 128 + colx];
#pragma unroll
    for (int i = 0; i < 2; ++i) {
      bf16x8 afr = *(const bf16x8*)&TA[(32 * wv + 16 * i + lr) * 128 + colx];
#pragma unroll
      for (int j = 0; j < 8; ++j)
        acc[i][j] = __builtin_amdgcn_mfma_f32_16x16x32_bf16(afr, bfr[j], acc[i][j], 0, 0, 0);
    }
  }
  __syncthreads();

#pragma unroll
  for (int i = 0; i < 2; ++i) {
    int c0 = 32 * wv + 16 * i + lg * 4;
#pragma unroll
    for (int j = 0; j < 8; ++j) {
      int v = 16 * j + lr;
      uint2 ov = make_uint2(pk2bf(acc[i][j][0], acc[i][j][1]),
                            pk2bf(acc[i][j][2], acc[i][j][3]));
      *(uint2*)&TA[v * 128 + (c0 ^ ((v & 7) << 3))] = ov;
    }
  }
#pragma unroll
  for (int r = 0; r < 8; ++r) {
    int idx = r * 256 + t;
    int row = idx >> 4, c8 = (idx & 15) * 8;
    *(u32x4*)&TB[row * 128 + (c8 ^ ((row & 7) << 3))] = *(const u32x4*)&Ap[row * 128 + c8];
  }
  __syncthreads();

#pragma unroll
  for (int i = 0; i < 2; ++i)
#pragma unroll
    for (int j = 0; j < 8; ++j) acc[i][j] = (f32x4){0.f, 0.f, 0.f, 0.f};
#pragma unroll
  for (int ks = 0; ks < 4; ++ks) {
    int colx = (ks * 32 + lg * 8) ^ ((lr & 7) << 3);
    bf16x8 bfr[8];
#pragma unroll
    for (int j = 0; j < 8; ++j)
      bfr[j] = *(const bf16x8*)&TA[(16 * j + lr) * 128 + colx];
#pragma unroll
    for (int i = 0; i < 2; ++i) {
      bf16x8 afr = *(const bf16x8*)&TB[(32 * wv + 16 * i + lr) * 128 + colx];
#pragma unroll
      for (int j = 0; j < 8; ++j)
        acc[i][j] = __builtin_amdgcn_mfma_f32_16x16x32_bf16(afr, bfr[j], acc[i][j], 0, 0, 0);
    }
  }
  __syncthreads();

  unsigned short* Os = S;               // [o][px] stride 136
  float* red1 = (float*)(S + 17408);
  float* red2 = red1 + 128 * 17;
  float s1p[8], s2p[8];
#pragma unroll
  for (int j = 0; j < 8; ++j) { s1p[j] = 0.f; s2p[j] = 0.f; }
#pragma unroll
  for (int i = 0; i < 2; ++i) {
    int o0 = 32 * wv + 16 * i + lg * 4;
    float bv[4];
#pragma unroll
    for (int r2 = 0; r2 < 4; ++r2) bv[r2] = pb[o0 + r2];
#pragma unroll
    for (int j = 0; j < 8; ++j) {
      int n = h * 128 + 16 * j + lr;
#pragma unroll
      for (int r2 = 0; r2 < 4; ++r2) {
        size_t off = (size_t)bg * CN + (size_t)(o0 + r2) * NN + n;
        float val = acc[i][j][r2] + bv[r2] + x[off];
        Os[(o0 + r2) * 136 + 16 * j + lr] = f2bf(val);
        s1p[j] += val;
        s2p[j] += val * val;
      }
    }
  }
#pragma unroll
  for (int j = 0; j < 8; ++j) {
    red1[(16 * j + lr) * 17 + (wv * 4 + lg)] = s1p[j];
    red2[(16 * j + lr) * 17 + (wv * 4 + lg)] = s2p[j];
  }
  __syncthreads();
#pragma unroll
  for (int r = 0; r < 8; ++r) {
    int idx = r * 256 + t;
    int row = idx >> 4, ch = idx & 15;
    unsigned short* op = out1 + (size_t)bg * CN + (size_t)row * NN + h * 128 + ch * 8;
    *(u32x4*)op = *(const u32x4*)&Os[row * 136 + ch * 8];
  }
  if (t < 128) {
    float s1 = 0.f, s2 = 0.f;
#pragma unroll
    for (int kk = 0; kk < 16; ++kk) { s1 += red1[t * 17 + kk]; s2 += red2[t * 17 + kk]; }
    float m = s1 * (1.f / 128.f);
    float var = s2 * (1.f / 128.f) - m * m;
    mu[(size_t)bg * NN + h * 128 + t] = m;
    rs[(size_t)bg * NN + h * 128 + t] = rsqrtf(var + 1e-5f);
  }
}

// ---- apply2 (MFMA): tmp[c][g*128+w] = sum_h attnT[g][h] * v2plane[h][w]; dense stores ----
__global__ __launch_bounds__(256) void k_apply2_mfma(unsigned short* __restrict__ buf,
                                                     const unsigned short* __restrict__ attnT,
                                                     int b0) {
  __shared__ unsigned short At[128 * 136];
  __shared__ unsigned short Bt[128 * 136];
  int bz = blockIdx.z, bg = b0 + bz, c = blockIdx.x;
  int t = threadIdx.x, w = t >> 6, l = t & 63, lr = l & 15, lg = l >> 4;
  const unsigned short* vsrc = buf + (size_t)bz * O3N + (size_t)(256 + c) * NN;
  const unsigned short* asrc = attnT + (size_t)bg * NN;
#pragma unroll
  for (int r = 0; r < 8; ++r) {
    int idx = r * 256 + t;
    int row = idx >> 4, c8 = (idx & 15) * 8;
    *(u32x4*)&At[row * 136 + c8] = *(const u32x4*)&asrc[row * 128 + c8];
    us4 lo = *(const us4*)&vsrc[row * 128 + c8];
    us4 hi = *(const us4*)&vsrc[row * 128 + c8 + 4];
#pragma unroll
    for (int q = 0; q < 4; ++q) {
      Bt[(c8 + q) * 136 + row] = lo[q];
      Bt[(c8 + 4 + q) * 136 + row] = hi[q];
    }
  }
  __syncthreads();
  f32x4 acc[2][8];
#pragma unroll
  for (int i = 0; i < 2; ++i)
#pragma unroll
    for (int j = 0; j < 8; ++j) acc[i][j] = (f32x4){0.f, 0.f, 0.f, 0.f};
#pragma unroll
  for (int ks = 0; ks < 4; ++ks) {
    bf16x8 bfr[8];
#pragma unroll
    for (int j = 0; j < 8; ++j)
      bfr[j] = *(const bf16x8*)&Bt[(16 * j + lr) * 136 + ks * 32 + lg * 8];
#pragma unroll
    for (int i = 0; i < 2; ++i) {
      bf16x8 afr = *(const bf16x8*)&At[(32 * w + 16 * i + lr) * 136 + ks * 32 + lg * 8];
#pragma unroll
      for (int j = 0; j < 8; ++j)
        acc[i][j] = __builtin_amdgcn_mfma_f32_16x16x32_bf16(afr, bfr[j], acc[i][j], 0, 0, 0);
    }
  }
  __syncthreads();
  unsigned short* Os = At;
#pragma unroll
  for (int i = 0; i < 2; ++i)
#pragma unroll
    for (int j = 0; j < 8; ++j) {
      int g = 32 * w + 16 * i + lg * 4;
      Os[g * 136 + 16 * j + lr] = f2bf(acc[i][j][0]);
      Os[(g + 1) * 136 + 16 * j + lr] = f2bf(acc[i][j][1]);
      Os[(g + 2) * 136 + 16 * j + lr] = f2bf(acc[i][j][2]);
      Os[(g + 3) * 136 + 16 * j + lr] = f2bf(acc[i][j][3]);
    }
  __syncthreads();
  unsigned short* ob = buf + (size_t)bz * O3N + (size_t)c * NN;
#pragma unroll
  for (int r = 0; r < 8; ++r) {
    int idx = r * 256 + t;
    int row = idx >> 4, ch = idx & 15;
    *(u32x4*)&ob[(size_t)row * 128 + ch * 8] = *(const u32x4*)&Os[row * 136 + ch * 8];
  }
}

// ---- proj (MFMA) + residual (bf16 res, fp32 dst); wide 4-px B loads ----
__global__ __launch_bounds__(256) void k_proj_mfma(
    const unsigned short* __restrict__ tin, const unsigned short* __restrict__ Ap,
    const float* __restrict__ pb, const unsigned short* __restrict__ res,
    float* __restrict__ dst, int b0) {
  __shared__ unsigned short Al[128 * 136];
  __shared__ unsigned short Bs2[64 * 128];
  int bz = blockIdx.z, bg = b0 + bz;
  int n0 = blockIdx.x * 64;
  int t = threadIdx.x, w = t >> 6, l = t & 63, lr = l & 15, lg = l >> 4;

#pragma unroll
  for (int r = 0; r < 8; ++r) {
    int v = r * 256 + t;
    int m = v >> 4, c8 = (v & 15) * 8;
    *(u32x4*)&Al[m * 136 + c8] = *(const u32x4*)&Ap[m * 128 + c8];
  }
  {
    int pg = t & 15, cbk = t >> 4;
    int c8 = cbk * 8;
    const unsigned short* tb = tin + (size_t)bz * O3N + n0 + pg * 4;
    us4 v[8];
#pragma unroll
    for (int ch = 0; ch < 8; ++ch)
      v[ch] = *(const us4*)&tb[(size_t)(c8 + ch) * NN];
#pragma unroll
    for (int pp = 0; pp < 4; ++pp) {
      unsigned pk[4];
#pragma unroll
      for (int q = 0; q < 4; ++q)
        pk[q] = (unsigned)v[2 * q][pp] | ((unsigned)v[2 * q + 1][pp] << 16);
      int n = pg * 4 + pp;
      *(u32x4*)&Bs2[n * 128 + (c8 ^ ((n & 7) << 3))] = *(const u32x4*)pk;
    }
  }
  __syncthreads();

  f32x4 acc[2][4];
#pragma unroll
  for (int i = 0; i < 2; ++i)
#pragma unroll
    for (int j = 0; j < 4; ++j) acc[i][j] = (f32x4){0.f, 0.f, 0.f, 0.f};

#pragma unroll
  for (int ks = 0; ks < 4; ++ks) {
    bf16x8 bfr[4];
#pragma unroll
    for (int j = 0; j < 4; ++j) {
      int row = 16 * j + lr;
      int col = (ks * 32 + lg * 8) ^ ((lr & 7) << 3);
      bfr[j] = *(const bf16x8*)&Bs2[row * 128 + col];
    }
#pragma unroll
    for (int i = 0; i < 2; ++i) {
      bf16x8 afr = *(const bf16x8*)&Al[(32 * w + 16 * i + lr) * 136 + ks * 32 + lg * 8];
#pragma unroll
      for (int j = 0; j < 4; ++j)
        acc[i][j] = __builtin_amdgcn_mfma_f32_16x16x32_bf16(afr, bfr[j], acc[i][j], 0, 0, 0);
    }
  }

#pragma unroll
  for (int i = 0; i < 2; ++i) {
    int ob = 32 * w + 16 * i + lg * 4;
    float bv[4];
#pragma unroll
    for (int r2 = 0; r2 < 4; ++r2) bv[r2] = pb[ob + r2];
#pragma unroll
    for (int j = 0; j < 4; ++j) {
      int n = n0 + 16 * j + lr;
#pragma unroll
      for (int r2 = 0; r2 < 4; ++r2) {
        size_t off = (size_t)bg * CN + (size_t)(ob + r2) * NN + n;
        dst[off] = acc[i][j][r2] + bv[r2] + bf2f(res[off]);
      }
    }
  }
}

extern "C" void kernel_launch(void* const* d_in, const int* in_sizes, int n_in,
                              void* d_out, int out_size, void* d_ws, size_t ws_size,
                              hipStream_t stream) {
  (void)in_sizes; (void)n_in; (void)out_size;
  const float* x     = (const float*)d_in[0];
  const float* lnw   = (const float*)d_in[1];
  const float* lnb   = (const float*)d_in[2];
  const float* qkvw  = (const float*)d_in[3];
  const float* qkvb  = (const float*)d_in[4];
  const float* dww   = (const float*)d_in[5];
  const float* dwb   = (const float*)d_in[6];
  const float* projw = (const float*)d_in[7];
  const float* projb = (const float*)d_in[8];
  const float* temp1 = (const float*)d_in[9];
  const float* temp2 = (const float*)d_in[10];
  float* out = (float*)d_out;
  float* ws = (float*)d_ws;

  auto needBytes = [&](int nb) {
    return ((size_t)nb * (O3N / 2) + 4ull * CN + 4ull * 131072 + 65536 + 768 + 24576 + 8192) * 4;
  };
  int NB = 8;
  while (NB > 1 && ws_size < needBytes(NB)) NB >>= 1;
  if (ws_size < needBytes(1)) return;

  unsigned short* convbuf = (unsigned short*)ws;
  unsigned short* out1 = (unsigned short*)(ws + (size_t)NB * (O3N / 2));
  float* mu = ws + (size_t)NB * (O3N / 2) + 4ull * CN;
  float* rs = mu + 131072;
  float* qm = rs + 131072;
  float* km = qm + 131072;
  unsigned short* attnT = (unsigned short*)(km + 131072);
  float* Svec  = (float*)(attnT + 8ull * NN);
  float* bias2 = Svec + 384;
  unsigned short* Aq = (unsigned short*)(bias2 + 384);
  unsigned short* Ap = Aq + 49152;

  k_prep<<<512, 64, 0, stream>>>(qkvw, qkvb, lnw, lnb, projw, Aq, Ap, Svec, bias2);

  // ---- stage 1 ----
  for (int b0 = 0; b0 < 8; b0 += NB) {
    k_qkv_mfma<<<dim3(256, 1, NB), 256, 0, stream>>>(x, mu, rs, Aq, Svec, bias2, convbuf,
                                                     b0, 0, 0);
    k_dwc<<<dim3(384, NB), 1024, 0, stream>>>(convbuf, dww, dwb, qm, km, b0, 0);
    k_norm2<<<dim3(NB * 128, 2), 64, 0, stream>>>(qm, km, b0 * 128);
    k_attn1<<<dim3(128, NB), 128, 0, stream>>>(qm, km, temp1, attnT, b0);
    k_ap1<<<dim3(128, 1, NB), 256, 0, stream>>>(convbuf, attnT, Ap, projb, x, out1, mu, rs, b0);
  }
  // ---- stage 2 ----
  for (int b0 = 0; b0 < 8; b0 += NB) {
    k_qkv_mfma<<<dim3(256, 1, NB), 256, 0, stream>>>(out1, mu, rs, Aq, Svec, bias2, convbuf,
                                                     b0, 1, 1);
    k_dwc<<<dim3(384, NB), 1024, 0, stream>>>(convbuf, dww, dwb, qm, km, b0, 1);
    k_reduce2<<<dim3(64, NB), 256, 0, stream>>>(convbuf, qm, km, b0);
    k_norm2<<<dim3(NB * 128, 2), 64, 0, stream>>>(qm, km, b0 * 128);
    k_attn2<<<dim3(128, NB), 128, 0, stream>>>(qm, km, temp2, attnT, b0);
    k_apply2_mfma<<<dim3(128, 1, NB), 256, 0, stream>>>(convbuf, attnT, b0);
    k_proj_mfma<<<dim3(256, 1, NB), 256, 0, stream>>>(convbuf, Ap, projb, out1, out, b0);
  }
}

// Round 14
// 274.411 us; speedup vs baseline: 1.1754x; 1.1122x over previous
//
#include <hip/hip_runtime.h>

typedef __attribute__((ext_vector_type(8))) short bf16x8;
typedef __attribute__((ext_vector_type(4))) float f32x4;
typedef __attribute__((ext_vector_type(4))) unsigned short us4;
typedef __attribute__((ext_vector_type(4))) unsigned int u32x4;

// dims
static constexpr int CC = 128, NN = 16384;       // C, H*W (H=W=128)
static constexpr int O3 = 384;                   // 3*C
static constexpr long long CN  = (long long)CC * NN;   // 2097152
static constexpr long long O3N = (long long)O3 * NN;   // 6291456

__device__ __forceinline__ float wave_sum(float v) {
  for (int o = 32; o; o >>= 1) v += __shfl_xor(v, o);
  return v;
}
__device__ __forceinline__ float wave_max(float v) {
  for (int o = 32; o; o >>= 1) v = fmaxf(v, __shfl_xor(v, o));
  return v;
}
__device__ __forceinline__ unsigned short f2bf(float f) {
  unsigned u = __float_as_uint(f);
  u += 0x7FFF + ((u >> 16) & 1);            // RNE
  return (unsigned short)(u >> 16);
}
__device__ __forceinline__ float bf2f(unsigned short h) {
  return __uint_as_float((unsigned)h << 16);
}

// ---- prep: A' = bf16(W*lnw), S[o] = sum(A'), bias2[o] = bq + sum(W*lnb); proj W -> bf16 ----
__global__ __launch_bounds__(64) void k_prep(const float* __restrict__ qkvw,
                                             const float* __restrict__ qkvb,
                                             const float* __restrict__ lnw,
                                             const float* __restrict__ lnb,
                                             const float* __restrict__ projw,
                                             unsigned short* __restrict__ Aq,
                                             unsigned short* __restrict__ Ap,
                                             float* __restrict__ Svec,
                                             float* __restrict__ bias2) {
  int o = blockIdx.x, t = threadIdx.x;
  if (o < O3) {
    float w0 = qkvw[o * 128 + t], w1 = qkvw[o * 128 + t + 64];
    unsigned short h0 = f2bf(w0 * lnw[t]), h1 = f2bf(w1 * lnw[t + 64]);
    Aq[o * 128 + t] = h0; Aq[o * 128 + t + 64] = h1;
    float s = wave_sum(bf2f(h0) + bf2f(h1));
    float bs = wave_sum(w0 * lnb[t] + w1 * lnb[t + 64]);
    if (t == 0) { Svec[o] = s; bias2[o] = qkvb[o] + bs; }
  } else {
    int r = o - O3;
    Ap[r * 128 + t] = f2bf(projw[r * 128 + t]);
    Ap[r * 128 + t + 64] = f2bf(projw[r * 128 + t + 64]);
  }
}

// ---- MFMA qkv GEMM, LN folded in epilogue, bf16 out. fp32 or bf16 input. ----
// Tile M=128 x N=64; 3 m-blocks per n-tile XCD-co-located (R8 structure).
__global__ __launch_bounds__(256) void k_qkv_mfma(
    const void* __restrict__ srcp, const float* __restrict__ mu, const float* __restrict__ rs,
    const unsigned short* __restrict__ Aq, const float* __restrict__ Svec,
    const float* __restrict__ bias2, unsigned short* __restrict__ out,
    int b0, int useg, int srcbf) {
  __shared__ unsigned short As[128 * 136];         // 34.8 KB
  __shared__ unsigned short Bs[64 * 128];          // [n][c], 8-ch blocks XOR-swizzled
  __shared__ float muL[64], rsL[64];
  int bz = blockIdx.z, bg = b0 + bz;
  int p = blockIdx.x;
  int hi = p / 24, rr0 = p - hi * 24;
  int m0 = (rr0 >> 3) * 128;
  int n0 = (hi * 8 + (rr0 & 7)) * 64;
  int t = threadIdx.x, w = t >> 6, l = t & 63;
  int lr = l & 15, lg = l >> 4;

  // stage A once: 128x128 bf16, coalesced 16B, stride 136
  {
    const unsigned short* Asrc = Aq + (size_t)m0 * 128;
#pragma unroll
    for (int r = 0; r < 8; ++r) {
      int v = r * 256 + t;
      int m = v >> 4, c8 = (v & 15) * 8;
      *(u32x4*)&As[m * 136 + c8] = *(const u32x4*)&Asrc[m * 128 + c8];
    }
  }
  // stage B: loads-first, pack -> swizzled LDS
  {
    int n = t & 63, cb = t >> 6;
    if (!srcbf) {
      const float* xb = (const float*)srcp + (size_t)bg * CN + n0;
      float xr[32];
#pragma unroll
      for (int g = 0; g < 4; ++g)
#pragma unroll
        for (int q = 0; q < 8; ++q)
          xr[g * 8 + q] = xb[(size_t)((cb * 4 + g) * 8 + q) * NN + n];
#pragma unroll
      for (int g = 0; g < 4; ++g) {
        int c8 = (cb * 4 + g) * 8;
        unsigned pk[4];
#pragma unroll
        for (int q = 0; q < 4; ++q) {
          unsigned short a = f2bf(xr[g * 8 + 2 * q]);
          unsigned short b = f2bf(xr[g * 8 + 2 * q + 1]);
          pk[q] = (unsigned)a | ((unsigned)b << 16);
        }
        int c8s = c8 ^ ((n & 7) << 3);
        *(u32x4*)&Bs[n * 128 + c8s] = *(const u32x4*)pk;
      }
    } else {
      const unsigned short* xb = (const unsigned short*)srcp + (size_t)bg * CN + n0;
      unsigned short xr[32];
#pragma unroll
      for (int g = 0; g < 4; ++g)
#pragma unroll
        for (int q = 0; q < 8; ++q)
          xr[g * 8 + q] = xb[(size_t)((cb * 4 + g) * 8 + q) * NN + n];
#pragma unroll
      for (int g = 0; g < 4; ++g) {
        int c8 = (cb * 4 + g) * 8;
        unsigned pk[4];
#pragma unroll
        for (int q = 0; q < 4; ++q)
          pk[q] = (unsigned)xr[g * 8 + 2 * q] | ((unsigned)xr[g * 8 + 2 * q + 1] << 16);
        int c8s = c8 ^ ((n & 7) << 3);
        *(u32x4*)&Bs[n * 128 + c8s] = *(const u32x4*)pk;
      }
    }
  }
  __syncthreads();

  // stage-1: in-block LN stats from the bf16 tile (4 threads per pixel)
  if (!useg) {
    int pp = t >> 2, sub = t & 3;
    float s1 = 0.f, s2 = 0.f;
#pragma unroll
    for (int b2 = 0; b2 < 4; ++b2) {
      int c8 = (sub * 4 + b2) * 8;
      int c8s = c8 ^ ((pp & 7) << 3);
      bf16x8 v = *(const bf16x8*)&Bs[pp * 128 + c8s];
#pragma unroll
      for (int q = 0; q < 8; ++q) {
        float f = bf2f((unsigned short)v[q]);
        s1 += f; s2 += f * f;
      }
    }
    s1 += __shfl_xor(s1, 1); s2 += __shfl_xor(s2, 1);
    s1 += __shfl_xor(s1, 2); s2 += __shfl_xor(s2, 2);
    if (sub == 0) {
      float m = s1 * (1.f / 128.f);
      muL[pp] = m;
      rsL[pp] = rsqrtf(s2 * (1.f / 128.f) - m * m + 1e-5f);
    }
    __syncthreads();
  }

  // MFMA: wave w covers rows m0+32w..+32 (2 frags) x 64 px (4 frags)
  f32x4 acc[2][4];
#pragma unroll
  for (int i = 0; i < 2; ++i)
#pragma unroll
    for (int j = 0; j < 4; ++j) acc[i][j] = (f32x4){0.f, 0.f, 0.f, 0.f};
#pragma unroll
  for (int ks = 0; ks < 4; ++ks) {
    bf16x8 bfr[4];
#pragma unroll
    for (int j = 0; j < 4; ++j) {
      int row = 16 * j + lr;
      int col = (ks * 32 + lg * 8) ^ ((lr & 7) << 3);
      bfr[j] = *(const bf16x8*)&Bs[row * 128 + col];
    }
#pragma unroll
    for (int i = 0; i < 2; ++i) {
      bf16x8 afr = *(const bf16x8*)&As[(32 * w + 16 * i + lr) * 136 + ks * 32 + lg * 8];
#pragma unroll
      for (int j = 0; j < 4; ++j)
        acc[i][j] = __builtin_amdgcn_mfma_f32_16x16x32_bf16(afr, bfr[j], acc[i][j], 0, 0, 0);
    }
  }

  // epilogue
  float rsv[4], muv[4];
#pragma unroll
  for (int j = 0; j < 4; ++j) {
    int nl = 16 * j + lr;
    if (useg) {
      rsv[j] = rs[(size_t)bg * NN + n0 + nl];
      muv[j] = mu[(size_t)bg * NN + n0 + nl];
    } else {
      rsv[j] = rsL[nl];
      muv[j] = muL[nl];
    }
  }
#pragma unroll
  for (int i = 0; i < 2; ++i) {
    int ob = m0 + 32 * w + 16 * i + lg * 4;
    float sv[4], bv[4];
#pragma unroll
    for (int r2 = 0; r2 < 4; ++r2) { sv[r2] = Svec[ob + r2]; bv[r2] = bias2[ob + r2]; }
#pragma unroll
    for (int j = 0; j < 4; ++j) {
      int n = n0 + 16 * j + lr;
      unsigned short* op = out + (size_t)bz * O3N + n;
#pragma unroll
      for (int r2 = 0; r2 < 4; ++r2)
        op[(size_t)(ob + r2) * NN] = f2bf(rsv[j] * (acc[i][j][r2] - muv[j] * sv[r2]) + bv[r2]);
    }
  }
}

// ---- 3x3 depthwise conv, bf16 in/out, padded-LDS (halo-only zero), fused stage-1 reductions ----
__global__ __launch_bounds__(1024) void k_dwc(unsigned short* __restrict__ buf,
                                              const float* __restrict__ dww,
                                              const float* __restrict__ dwb,
                                              float* __restrict__ qm,
                                              float* __restrict__ km,
                                              int b0, int stage) {
  __shared__ unsigned short pl[130 * 144];         // rows -1..128, cols -8..135 (72 u32/row)
  __shared__ float red[32 * 128];
  int o = blockIdx.x, bz = blockIdx.y, bg = b0 + bz;
  int t = threadIdx.x;
  unsigned short* base = buf + (size_t)bz * O3N + (size_t)o * NN;
  unsigned* pl32 = (unsigned*)pl;

  for (int i = t; i < 1168; i += 1024) {
    int idx;
    if (i < 72) idx = i;
    else if (i < 144) idx = 129 * 72 + (i - 72);
    else { int j = i - 144; int row = (j >> 3) + 1; int s = j & 7;
           idx = row * 72 + (s < 4 ? s : 64 + s); }
    pl32[idx] = 0u;
  }
  __syncthreads();
#pragma unroll
  for (int r = 0; r < 2; ++r) {
    int idx = r * 1024 + t;
    int row = idx >> 4, c8 = (idx & 15) * 8;
    *(u32x4*)&pl[(row + 1) * 144 + 8 + c8] = *(const u32x4*)&base[row * 128 + c8];
  }
  __syncthreads();

  const float* wg = dww + o * 9;
  float w00 = wg[0], w01 = wg[1], w02 = wg[2];
  float w10 = wg[3], w11 = wg[4], w12 = wg[5];
  float w20 = wg[6], w21 = wg[7], w22 = wg[8];
  float bias = dwb[o];
  int mode = (stage == 0) ? (o < 128 ? 1 : (o < 256 ? 2 : 0)) : 0;
  int hh0 = t >> 5, w0 = (t & 31) * 4;
  float csum[4] = {0.f, 0.f, 0.f, 0.f};
  float cmax[4] = {-1e30f, -1e30f, -1e30f, -1e30f};

#pragma unroll
  for (int g = 0; g < 4; ++g) {
    int h = g * 32 + hh0;
    float a0 = bias, a1 = bias, a2 = bias, a3 = bias;
#pragma unroll
    for (int dr = 0; dr < 3; ++dr) {
      const unsigned short* rp = &pl[(h + dr) * 144];
      us4 cA = *(const us4*)&rp[w0 + 4];
      us4 cB = *(const us4*)&rp[w0 + 8];
      us4 cC = *(const us4*)&rp[w0 + 12];
      float f0 = bf2f(cA[3]), f1 = bf2f(cB[0]), f2 = bf2f(cB[1]);
      float f3 = bf2f(cB[2]), f4 = bf2f(cB[3]), f5 = bf2f(cC[0]);
      float wr0 = (dr == 0) ? w00 : (dr == 1 ? w10 : w20);
      float wr1 = (dr == 0) ? w01 : (dr == 1 ? w11 : w21);
      float wr2 = (dr == 0) ? w02 : (dr == 1 ? w12 : w22);
      a0 += f0 * wr0 + f1 * wr1 + f2 * wr2;
      a1 += f1 * wr0 + f2 * wr1 + f3 * wr2;
      a2 += f2 * wr0 + f3 * wr1 + f4 * wr2;
      a3 += f3 * wr0 + f4 * wr1 + f5 * wr2;
    }
    if (mode == 0) {
      us4 ov;
      ov[0] = f2bf(a0); ov[1] = f2bf(a1); ov[2] = f2bf(a2); ov[3] = f2bf(a3);
      *(us4*)&base[g * 4096 + t * 4] = ov;
    } else if (mode == 1) {
      csum[0] += a0; csum[1] += a1; csum[2] += a2; csum[3] += a3;
    } else {
      cmax[0] = fmaxf(cmax[0], a0); cmax[1] = fmaxf(cmax[1], a1);
      cmax[2] = fmaxf(cmax[2], a2); cmax[3] = fmaxf(cmax[3], a3);
    }
  }

  if (mode) {
    int j = t >> 5;
#pragma unroll
    for (int dx = 0; dx < 4; ++dx)
      red[j * 128 + w0 + dx] = (mode == 1) ? csum[dx] : cmax[dx];
    __syncthreads();
    if (t < 128) {
      float v = red[t];
      if (mode == 1) {
        for (int jj = 1; jj < 32; ++jj) v += red[jj * 128 + t];
        qm[(size_t)bg * NN + o * 128 + t] = v * (1.f / 128.f);
      } else {
        for (int jj = 1; jj < 32; ++jj) v = fmaxf(v, red[jj * 128 + t]);
        km[(size_t)bg * NN + (o - 128) * 128 + t] = v;
      }
    }
  }
}

// ---- stage-2 reductions: mean over channels of bf16 q,k planes -> [b, h, w] ----
__global__ __launch_bounds__(256) void k_reduce2(const unsigned short* __restrict__ qkv,
                                                 float* __restrict__ qm, float* __restrict__ km,
                                                 int b0) {
  int bz = blockIdx.y;
  int n = blockIdx.x * 256 + threadIdx.x;
  const unsigned short* base = qkv + (size_t)bz * O3N + n;
  float sq = 0.f, sk = 0.f;
#pragma unroll 4
  for (int c = 0; c < 128; ++c) {
    sq += bf2f(base[(size_t)c * NN]);
    sk += bf2f(base[(size_t)(c + 128) * NN]);
  }
  size_t off = (size_t)(b0 + bz) * NN + n;
  qm[off] = sq * (1.f / 128.f);
  km[off] = sk * (1.f / 128.f);
}

// ---- l2-normalize rows of length 128 in place ----
__global__ void k_norm2(float* __restrict__ qm, float* __restrict__ km, int row0) {
  float* buf = blockIdx.y ? km : qm;
  int r = row0 + blockIdx.x, t = threadIdx.x;   // 64 threads
  float* p = buf + (size_t)r * 128;
  float v0 = p[t], v1 = p[t + 64];
  float s = wave_sum(v0 * v0 + v1 * v1);
  float sc = 1.f / fmaxf(sqrtf(s), 1e-12f);
  p[t] = v0 * sc;
  p[t + 64] = v1 * sc;
}

// ---- attn1: scores over c; writes attnT[v][w] bf16 ----
__global__ void k_attn1(const float* __restrict__ qm, const float* __restrict__ km,
                        const float* __restrict__ temp, unsigned short* __restrict__ attnT,
                        int b0) {
  int bg = b0 + blockIdx.y;
  int i = blockIdx.x, t = threadIdx.x;          // i = w (query), t = v (key)
  const float* qb = qm + (size_t)bg * NN;
  const float* kb = km + (size_t)bg * NN;
  __shared__ float qcol[128];
  __shared__ float wred[2];
  qcol[t] = qb[t * 128 + i];
  __syncthreads();
  float s = 0.f;
#pragma unroll 4
  for (int k = 0; k < 128; ++k) s += qcol[k] * kb[k * 128 + t];
  s *= temp[0];
  int wid = t >> 6, lane = t & 63;
  float mx = wave_max(s);
  if (lane == 0) wred[wid] = mx;
  __syncthreads();
  mx = fmaxf(wred[0], wred[1]);
  float pv = __expf(s - mx);
  __syncthreads();
  float sm = wave_sum(pv);
  if (lane == 0) wred[wid] = sm;
  __syncthreads();
  float denom = wred[0] + wred[1];
  attnT[(size_t)bg * NN + (size_t)t * 128 + i] = f2bf(pv / denom);
}

// ---- attn2: scores over w; writes attnT[g][h] bf16 ----
__global__ void k_attn2(const float* __restrict__ qm, const float* __restrict__ km,
                        const float* __restrict__ temp, unsigned short* __restrict__ attnT,
                        int b0) {
  int bg = b0 + blockIdx.y;
  int i = blockIdx.x, t = threadIdx.x;          // i = h, t = g
  const float* qb = qm + (size_t)bg * NN + i * 128;
  const float* kb = km + (size_t)bg * NN + (size_t)t * 128;
  __shared__ float qrow[128];
  __shared__ float wred[2];
  qrow[t] = qb[t];
  __syncthreads();
  float s = 0.f;
#pragma unroll 4
  for (int w = 0; w < 128; ++w) s += qrow[w] * kb[w];
  s *= temp[0];
  int wid = t >> 6, lane = t & 63;
  float mx = wave_max(s);
  if (lane == 0) wred[wid] = mx;
  __syncthreads();
  mx = fmaxf(wred[0], wred[1]);
  float pv = __expf(s - mx);
  __syncthreads();
  float sm = wave_sum(pv);
  if (lane == 0) wred[wid] = sm;
  __syncthreads();
  float denom = wred[0] + wred[1];
  attnT[(size_t)bg * NN + (size_t)t * 128 + i] = f2bf(pv / denom);
}

// ---- FUSED stage-1 apply+proj+stats: one block per h-row. ----
// GEMM1: tmp[c][v] = sum_w v1[(c,h)][w] * attnT[v][w]
// GEMM2: out1[o][h,v] = bf16( sum_c Ap[o][c]*tmp[c][v] + pb[o] + x[o][h,v] ); LN stats of out1.
__global__ __launch_bounds__(256) void k_ap1(const unsigned short* __restrict__ buf,
                                             const unsigned short* __restrict__ attnT,
                                             const unsigned short* __restrict__ Ap,
                                             const float* __restrict__ pb,
                                             const float* __restrict__ x,
                                             unsigned short* __restrict__ out1,
                                             float* __restrict__ mu, float* __restrict__ rs,
                                             int b0) {
  __shared__ __attribute__((aligned(16))) unsigned short S[32768];   // 64 KB, two 32KB tiles
  unsigned short* TA = S;            // GEMM1 A (v1 rows), then tmpT [v][c]
  unsigned short* TB = S + 16384;    // GEMM1 B (attnT), then Ap [o][c]
  int h = blockIdx.x, bz = blockIdx.z, bg = b0 + bz;
  int t = threadIdx.x, wv = t >> 6, l = t & 63, lr = l & 15, lg = l >> 4;

  // stage A1 (v1 rows m=c*128+h) and B1 (attnT), XOR-swizzled 8-col granules
  {
    const unsigned short* vbase = buf + (size_t)bz * O3N + (size_t)256 * NN;
    const unsigned short* abase = attnT + (size_t)bg * NN;
#pragma unroll
    for (int r = 0; r < 8; ++r) {
      int idx = r * 256 + t;
      int row = idx >> 4, c8 = (idx & 15) * 8;
      int c8s = c8 ^ ((row & 7) << 3);
      *(u32x4*)&TA[row * 128 + c8s] = *(const u32x4*)&vbase[((size_t)row * 128 + h) * 128 + c8];
      *(u32x4*)&TB[row * 128 + c8s] = *(const u32x4*)&abase[row * 128 + c8];
    }
  }
  __syncthreads();

  // GEMM1: rows c = 32wv+16i+..., cols v (8 j-frags), K = w
  f32x4 acc[2][8];
#pragma unroll
  for (int i = 0; i < 2; ++i)
#pragma unroll
    for (int j = 0; j < 8; ++j) acc[i][j] = (f32x4){0.f, 0.f, 0.f, 0.f};
#pragma unroll
  for (int ks = 0; ks < 4; ++ks) {
    int colx = (ks * 32 + lg * 8) ^ ((lr & 7) << 3);
    bf16x8 bfr[8];
#pragma unroll
    for (int j = 0; j < 8; ++j)
      bfr[j] = *(const bf16x8*)&TB[(16 * j + lr) * 128 + colx];
#pragma unroll
    for (int i = 0; i < 2; ++i) {
      bf16x8 afr = *(const bf16x8*)&TA[(32 * wv + 16 * i + lr) * 128 + colx];
#pragma unroll
      for (int j = 0; j < 8; ++j)
        acc[i][j] = __builtin_amdgcn_mfma_f32_16x16x32_bf16(afr, bfr[j], acc[i][j], 0, 0, 0);
    }
  }
  __syncthreads();   // TA/TB dead

  // write tmpT [v][c] into TA; stage Ap into TB
#pragma unroll
  for (int i = 0; i < 2; ++i) {
    int c0 = 32 * wv + 16 * i + lg * 4;
#pragma unroll
    for (int j = 0; j < 8; ++j) {
      int v = 16 * j + lr;
      us4 ov;
#pragma unroll
      for (int r2 = 0; r2 < 4; ++r2) ov[r2] = f2bf(acc[i][j][r2]);
      *(us4*)&TA[v * 128 + (c0 ^ ((v & 7) << 3))] = ov;
    }
  }
#pragma unroll
  for (int r = 0; r < 8; ++r) {
    int idx = r * 256 + t;
    int row = idx >> 4, c8 = (idx & 15) * 8;
    *(u32x4*)&TB[row * 128 + (c8 ^ ((row & 7) << 3))] = *(const u32x4*)&Ap[row * 128 + c8];
  }
  __syncthreads();

  // GEMM2: rows o, cols v, K = c
#pragma unroll
  for (int i = 0; i < 2; ++i)
#pragma unroll
    for (int j = 0; j < 8; ++j) acc[i][j] = (f32x4){0.f, 0.f, 0.f, 0.f};
#pragma unroll
  for (int ks = 0; ks < 4; ++ks) {
    int colx = (ks * 32 + lg * 8) ^ ((lr & 7) << 3);
    bf16x8 bfr[8];
#pragma unroll
    for (int j = 0; j < 8; ++j)
      bfr[j] = *(const bf16x8*)&TA[(16 * j + lr) * 128 + colx];
#pragma unroll
    for (int i = 0; i < 2; ++i) {
      bf16x8 afr = *(const bf16x8*)&TB[(32 * wv + 16 * i + lr) * 128 + colx];
#pragma unroll
      for (int j = 0; j < 8; ++j)
        acc[i][j] = __builtin_amdgcn_mfma_f32_16x16x32_bf16(afr, bfr[j], acc[i][j], 0, 0, 0);
    }
  }

  // epilogue: +bias +residual(x fp32), write out1 bf16, accumulate stats
  float s1p[8], s2p[8];
#pragma unroll
  for (int j = 0; j < 8; ++j) { s1p[j] = 0.f; s2p[j] = 0.f; }
#pragma unroll
  for (int i = 0; i < 2; ++i) {
    int o0 = 32 * wv + 16 * i + lg * 4;
    float bv[4];
#pragma unroll
    for (int r2 = 0; r2 < 4; ++r2) bv[r2] = pb[o0 + r2];
#pragma unroll
    for (int j = 0; j < 8; ++j) {
      int n = h * 128 + 16 * j + lr;
#pragma unroll
      for (int r2 = 0; r2 < 4; ++r2) {
        size_t off = (size_t)bg * CN + (size_t)(o0 + r2) * NN + n;
        float val = acc[i][j][r2] + bv[r2] + x[off];
        out1[off] = f2bf(val);
        s1p[j] += val;
        s2p[j] += val * val;
      }
    }
  }
  __syncthreads();   // TA/TB dead -> overlay reduction arrays
  float* red1 = (float*)S;              // [128][17]
  float* red2 = red1 + 128 * 17;
#pragma unroll
  for (int j = 0; j < 8; ++j) {
    red1[(16 * j + lr) * 17 + (wv * 4 + lg)] = s1p[j];
    red2[(16 * j + lr) * 17 + (wv * 4 + lg)] = s2p[j];
  }
  __syncthreads();
  if (t < 128) {
    float s1 = 0.f, s2 = 0.f;
#pragma unroll
    for (int kk = 0; kk < 16; ++kk) { s1 += red1[t * 17 + kk]; s2 += red2[t * 17 + kk]; }
    float m = s1 * (1.f / 128.f);
    float var = s2 * (1.f / 128.f) - m * m;
    mu[(size_t)bg * NN + h * 128 + t] = m;
    rs[(size_t)bg * NN + h * 128 + t] = rsqrtf(var + 1e-5f);
  }
}

// ---- apply2 (MFMA): tmp[c][g*128+w] = sum_h attnT[g][h] * v2plane[h][w] ----
__global__ __launch_bounds__(256) void k_apply2_mfma(unsigned short* __restrict__ buf,
                                                     const unsigned short* __restrict__ attnT,
                                                     int b0) {
  __shared__ unsigned short At[128 * 136];
  __shared__ unsigned short Bt[128 * 136];       // v2 plane transposed [w][h]
  int bz = blockIdx.z, bg = b0 + bz, c = blockIdx.x;
  int t = threadIdx.x, w = t >> 6, l = t & 63, lr = l & 15, lg = l >> 4;
  const unsigned short* vsrc = buf + (size_t)bz * O3N + (size_t)(256 + c) * NN;
  const unsigned short* asrc = attnT + (size_t)bg * NN;
#pragma unroll
  for (int r = 0; r < 8; ++r) {
    int idx = r * 256 + t;
    int row = idx >> 4, c8 = (idx & 15) * 8;
    *(u32x4*)&At[row * 136 + c8] = *(const u32x4*)&asrc[row * 128 + c8];
    us4 lo = *(const us4*)&vsrc[row * 128 + c8];
    us4 hi = *(const us4*)&vsrc[row * 128 + c8 + 4];
#pragma unroll
    for (int q = 0; q < 4; ++q) {
      Bt[(c8 + q) * 136 + row] = lo[q];
      Bt[(c8 + 4 + q) * 136 + row] = hi[q];
    }
  }
  __syncthreads();
  f32x4 acc[2][8];
#pragma unroll
  for (int i = 0; i < 2; ++i)
#pragma unroll
    for (int j = 0; j < 8; ++j) acc[i][j] = (f32x4){0.f, 0.f, 0.f, 0.f};
#pragma unroll
  for (int ks = 0; ks < 4; ++ks) {
    bf16x8 bfr[8];
#pragma unroll
    for (int j = 0; j < 8; ++j)
      bfr[j] = *(const bf16x8*)&Bt[(16 * j + lr) * 136 + ks * 32 + lg * 8];
#pragma unroll
    for (int i = 0; i < 2; ++i) {
      bf16x8 afr = *(const bf16x8*)&At[(32 * w + 16 * i + lr) * 136 + ks * 32 + lg * 8];
#pragma unroll
      for (int j = 0; j < 8; ++j)
        acc[i][j] = __builtin_amdgcn_mfma_f32_16x16x32_bf16(afr, bfr[j], acc[i][j], 0, 0, 0);
    }
  }
  unsigned short* ob = buf + (size_t)bz * O3N + (size_t)c * NN;  // q-region plane c
#pragma unroll
  for (int i = 0; i < 2; ++i)
#pragma unroll
    for (int j = 0; j < 8; ++j)
#pragma unroll
      for (int r2 = 0; r2 < 4; ++r2) {
        int g = 32 * w + 16 * i + lg * 4 + r2;
        int n = 16 * j + lr;
        ob[(size_t)g * 128 + n] = f2bf(acc[i][j][r2]);
      }
}

// ---- proj (MFMA) + residual (bf16 res, fp32 dst) ----
__global__ __launch_bounds__(256) void k_proj_mfma(
    const unsigned short* __restrict__ tin, const unsigned short* __restrict__ Ap,
    const float* __restrict__ pb, const unsigned short* __restrict__ res,
    float* __restrict__ dst, int b0) {
  __shared__ unsigned short Al[128 * 136];
  __shared__ unsigned short Bs2[64 * 128];
  int bz = blockIdx.z, bg = b0 + bz;
  int n0 = blockIdx.x * 64;
  int t = threadIdx.x, w = t >> 6, l = t & 63, lr = l & 15, lg = l >> 4;
  const unsigned short* tb = tin + (size_t)bz * O3N + n0;

#pragma unroll
  for (int r = 0; r < 8; ++r) {
    int v = r * 256 + t;
    int m = v >> 4, c8 = (v & 15) * 8;
    *(u32x4*)&Al[m * 136 + c8] = *(const u32x4*)&Ap[m * 128 + c8];
  }
  {
    int n = t & 63, cb = t >> 6;
    unsigned short vr[32];
#pragma unroll
    for (int g = 0; g < 4; ++g)
#pragma unroll
      for (int q = 0; q < 8; ++q)
        vr[g * 8 + q] = tb[(size_t)((cb * 4 + g) * 8 + q) * NN + n];
#pragma unroll
    for (int g = 0; g < 4; ++g) {
      int c8 = (cb * 4 + g) * 8;
      unsigned pk[4];
#pragma unroll
      for (int q = 0; q < 4; ++q)
        pk[q] = (unsigned)vr[g * 8 + 2 * q] | ((unsigned)vr[g * 8 + 2 * q + 1] << 16);
      int c8s = c8 ^ ((n & 7) << 3);
      *(u32x4*)&Bs2[n * 128 + c8s] = *(const u32x4*)pk;
    }
  }
  __syncthreads();

  f32x4 acc[2][4];
#pragma unroll
  for (int i = 0; i < 2; ++i)
#pragma unroll
    for (int j = 0; j < 4; ++j) acc[i][j] = (f32x4){0.f, 0.f, 0.f, 0.f};

#pragma unroll
  for (int ks = 0; ks < 4; ++ks) {
    bf16x8 bfr[4];
#pragma unroll
    for (int j = 0; j < 4; ++j) {
      int row = 16 * j + lr;
      int col = (ks * 32 + lg * 8) ^ ((lr & 7) << 3);
      bfr[j] = *(const bf16x8*)&Bs2[row * 128 + col];
    }
#pragma unroll
    for (int i = 0; i < 2; ++i) {
      bf16x8 afr = *(const bf16x8*)&Al[(32 * w + 16 * i + lr) * 136 + ks * 32 + lg * 8];
#pragma unroll
      for (int j = 0; j < 4; ++j)
        acc[i][j] = __builtin_amdgcn_mfma_f32_16x16x32_bf16(afr, bfr[j], acc[i][j], 0, 0, 0);
    }
  }

#pragma unroll
  for (int i = 0; i < 2; ++i) {
    int ob = 32 * w + 16 * i + lg * 4;
    float bv[4];
#pragma unroll
    for (int r2 = 0; r2 < 4; ++r2) bv[r2] = pb[ob + r2];
#pragma unroll
    for (int j = 0; j < 4; ++j) {
      int n = n0 + 16 * j + lr;
#pragma unroll
      for (int r2 = 0; r2 < 4; ++r2) {
        size_t off = (size_t)bg * CN + (size_t)(ob + r2) * NN + n;
        dst[off] = acc[i][j][r2] + bv[r2] + bf2f(res[off]);
      }
    }
  }
}

extern "C" void kernel_launch(void* const* d_in, const int* in_sizes, int n_in,
                              void* d_out, int out_size, void* d_ws, size_t ws_size,
                              hipStream_t stream) {
  (void)in_sizes; (void)n_in; (void)out_size;
  const float* x     = (const float*)d_in[0];
  const float* lnw   = (const float*)d_in[1];
  const float* lnb   = (const float*)d_in[2];
  const float* qkvw  = (const float*)d_in[3];
  const float* qkvb  = (const float*)d_in[4];
  const float* dww   = (const float*)d_in[5];
  const float* dwb   = (const float*)d_in[6];
  const float* projw = (const float*)d_in[7];
  const float* projb = (const float*)d_in[8];
  const float* temp1 = (const float*)d_in[9];
  const float* temp2 = (const float*)d_in[10];
  float* out = (float*)d_out;
  float* ws = (float*)d_ws;

  // floats: convbuf bf16 (nb*O3N/2) + out1 bf16 (8*CN/2 = 4*CN) + mu,rs,qm,km + attnT + consts
  auto needBytes = [&](int nb) {
    return ((size_t)nb * (O3N / 2) + 4ull * CN + 4ull * 131072 + 65536 + 768 + 24576 + 8192) * 4;
  };
  int NB = 8;
  while (NB > 1 && ws_size < needBytes(NB)) NB >>= 1;
  if (ws_size < needBytes(1)) return;

  unsigned short* convbuf = (unsigned short*)ws;
  unsigned short* out1 = (unsigned short*)(ws + (size_t)NB * (O3N / 2));
  float* mu = ws + (size_t)NB * (O3N / 2) + 4ull * CN;
  float* rs = mu + 131072;
  float* qm = rs + 131072;
  float* km = qm + 131072;
  unsigned short* attnT = (unsigned short*)(km + 131072);
  float* Svec  = (float*)(attnT + 8ull * NN);
  float* bias2 = Svec + 384;
  unsigned short* Aq = (unsigned short*)(bias2 + 384);
  unsigned short* Ap = Aq + 49152;

  k_prep<<<512, 64, 0, stream>>>(qkvw, qkvb, lnw, lnb, projw, Aq, Ap, Svec, bias2);

  // ---- stage 1 ----
  for (int b0 = 0; b0 < 8; b0 += NB) {
    k_qkv_mfma<<<dim3(768, 1, NB), 256, 0, stream>>>(x, mu, rs, Aq, Svec, bias2, convbuf,
                                                     b0, 0, 0);
    k_dwc<<<dim3(384, NB), 1024, 0, stream>>>(convbuf, dww, dwb, qm, km, b0, 0);
    k_norm2<<<dim3(NB * 128, 2), 64, 0, stream>>>(qm, km, b0 * 128);
    k_attn1<<<dim3(128, NB), 128, 0, stream>>>(qm, km, temp1, attnT, b0);
    k_ap1<<<dim3(128, 1, NB), 256, 0, stream>>>(convbuf, attnT, Ap, projb, x, out1, mu, rs, b0);
  }
  // ---- stage 2 ----
  for (int b0 = 0; b0 < 8; b0 += NB) {
    k_qkv_mfma<<<dim3(768, 1, NB), 256, 0, stream>>>(out1, mu, rs, Aq, Svec, bias2, convbuf,
                                                     b0, 1, 1);
    k_dwc<<<dim3(384, NB), 1024, 0, stream>>>(convbuf, dww, dwb, qm, km, b0, 1);
    k_reduce2<<<dim3(64, NB), 256, 0, stream>>>(convbuf, qm, km, b0);
    k_norm2<<<dim3(NB * 128, 2), 64, 0, stream>>>(qm, km, b0 * 128);
    k_attn2<<<dim3(128, NB), 128, 0, stream>>>(qm, km, temp2, attnT, b0);
    k_apply2_mfma<<<dim3(128, 1, NB), 256, 0, stream>>>(convbuf, attnT, b0);
    k_proj_mfma<<<dim3(256, 1, NB), 256, 0, stream>>>(convbuf, Ap, projb, out1, out, b0);
  }
}

// Round 15
// 271.987 us; speedup vs baseline: 1.1858x; 1.0089x over previous
//
#include <hip/hip_runtime.h>

typedef __attribute__((ext_vector_type(8))) short bf16x8;
typedef __attribute__((ext_vector_type(4))) float f32x4;
typedef __attribute__((ext_vector_type(4))) unsigned short us4;
typedef __attribute__((ext_vector_type(4))) unsigned int u32x4;

// dims
static constexpr int CC = 128, NN = 16384;       // C, H*W (H=W=128)
static constexpr int O3 = 384;                   // 3*C
static constexpr long long CN  = (long long)CC * NN;   // 2097152
static constexpr long long O3N = (long long)O3 * NN;   // 6291456

__device__ __forceinline__ float wave_sum(float v) {
  for (int o = 32; o; o >>= 1) v += __shfl_xor(v, o);
  return v;
}
__device__ __forceinline__ float wave_max(float v) {
  for (int o = 32; o; o >>= 1) v = fmaxf(v, __shfl_xor(v, o));
  return v;
}
__device__ __forceinline__ unsigned short f2bf(float f) {
  unsigned u = __float_as_uint(f);
  u += 0x7FFF + ((u >> 16) & 1);            // RNE
  return (unsigned short)(u >> 16);
}
__device__ __forceinline__ float bf2f(unsigned short h) {
  return __uint_as_float((unsigned)h << 16);
}
// async global->LDS, 16B per lane; LDS dest = wave-uniform base + lane*16
__device__ __forceinline__ void gl_lds16(const void* g, void* l) {
  __builtin_amdgcn_global_load_lds(
      (const __attribute__((address_space(1))) unsigned int*)g,
      (__attribute__((address_space(3))) unsigned int*)l, 16, 0, 0);
}

// ---- prep: A' = bf16(W*lnw) PRE-SWIZZLED (8-block XOR row&7), S, bias2; proj W swizzled ----
__global__ __launch_bounds__(64) void k_prep(const float* __restrict__ qkvw,
                                             const float* __restrict__ qkvb,
                                             const float* __restrict__ lnw,
                                             const float* __restrict__ lnb,
                                             const float* __restrict__ projw,
                                             unsigned short* __restrict__ Aq,
                                             unsigned short* __restrict__ Ap,
                                             float* __restrict__ Svec,
                                             float* __restrict__ bias2) {
  int o = blockIdx.x, t = threadIdx.x;
  if (o < O3) {
    float w0 = qkvw[o * 128 + t], w1 = qkvw[o * 128 + t + 64];
    unsigned short h0 = f2bf(w0 * lnw[t]), h1 = f2bf(w1 * lnw[t + 64]);
    int c1 = t + 64;
    int c0s = (((t >> 3) ^ (o & 7)) << 3) | (t & 7);
    int c1s = (((c1 >> 3) ^ (o & 7)) << 3) | (c1 & 7);
    Aq[o * 128 + c0s] = h0; Aq[o * 128 + c1s] = h1;
    float s = wave_sum(bf2f(h0) + bf2f(h1));
    float bs = wave_sum(w0 * lnb[t] + w1 * lnb[t + 64]);
    if (t == 0) { Svec[o] = s; bias2[o] = qkvb[o] + bs; }
  } else {
    int r = o - O3;
    int c1 = t + 64;
    int c0s = (((t >> 3) ^ (r & 7)) << 3) | (t & 7);
    int c1s = (((c1 >> 3) ^ (r & 7)) << 3) | (c1 & 7);
    Ap[r * 128 + c0s] = f2bf(projw[r * 128 + t]);
    Ap[r * 128 + c1s] = f2bf(projw[r * 128 + t + 64]);
  }
}

// ---- MFMA qkv GEMM, LN folded in epilogue, bf16 out. fp32 or bf16 input. ----
// Tile M=128 x N=64; 3 m-blocks per n-tile XCD-co-located. A via global_load_lds (linear).
__global__ __launch_bounds__(256) void k_qkv_mfma(
    const void* __restrict__ srcp, const float* __restrict__ mu, const float* __restrict__ rs,
    const unsigned short* __restrict__ Aq, const float* __restrict__ Svec,
    const float* __restrict__ bias2, unsigned short* __restrict__ out,
    int b0, int useg, int srcbf) {
  __shared__ unsigned short As[128 * 128];         // 32 KB, linear (pre-swizzled content)
  __shared__ unsigned short Bs[64 * 128];          // [n][c], 8-ch blocks XOR-swizzled
  __shared__ float muL[64], rsL[64];
  int bz = blockIdx.z, bg = b0 + bz;
  int p = blockIdx.x;
  int hi = p / 24, rr0 = p - hi * 24;
  int m0 = (rr0 >> 3) * 128;
  int n0 = (hi * 8 + (rr0 & 7)) * 64;
  int t = threadIdx.x, w = t >> 6, l = t & 63;
  int lr = l & 15, lg = l >> 4;

  // stage A: async direct-to-LDS, 8 x 1KB per wave, linear dest
  {
    const unsigned short* Asrc = Aq + (size_t)m0 * 128;
#pragma unroll
    for (int r = 0; r < 8; ++r) {
      int v = r * 256 + t;
      gl_lds16(&Asrc[(size_t)v * 8], &As[(size_t)(r * 256 + (t & 192)) * 8]);
    }
  }
  // stage B: loads-first, pack -> swizzled LDS
  {
    int n = t & 63, cb = t >> 6;
    if (!srcbf) {
      const float* xb = (const float*)srcp + (size_t)bg * CN + n0;
      float xr[32];
#pragma unroll
      for (int g = 0; g < 4; ++g)
#pragma unroll
        for (int q = 0; q < 8; ++q)
          xr[g * 8 + q] = xb[(size_t)((cb * 4 + g) * 8 + q) * NN + n];
#pragma unroll
      for (int g = 0; g < 4; ++g) {
        int c8 = (cb * 4 + g) * 8;
        unsigned pk[4];
#pragma unroll
        for (int q = 0; q < 4; ++q) {
          unsigned short a = f2bf(xr[g * 8 + 2 * q]);
          unsigned short b = f2bf(xr[g * 8 + 2 * q + 1]);
          pk[q] = (unsigned)a | ((unsigned)b << 16);
        }
        int c8s = c8 ^ ((n & 7) << 3);
        *(u32x4*)&Bs[n * 128 + c8s] = *(const u32x4*)pk;
      }
    } else {
      const unsigned short* xb = (const unsigned short*)srcp + (size_t)bg * CN + n0;
      unsigned short xr[32];
#pragma unroll
      for (int g = 0; g < 4; ++g)
#pragma unroll
        for (int q = 0; q < 8; ++q)
          xr[g * 8 + q] = xb[(size_t)((cb * 4 + g) * 8 + q) * NN + n];
#pragma unroll
      for (int g = 0; g < 4; ++g) {
        int c8 = (cb * 4 + g) * 8;
        unsigned pk[4];
#pragma unroll
        for (int q = 0; q < 4; ++q)
          pk[q] = (unsigned)xr[g * 8 + 2 * q] | ((unsigned)xr[g * 8 + 2 * q + 1] << 16);
        int c8s = c8 ^ ((n & 7) << 3);
        *(u32x4*)&Bs[n * 128 + c8s] = *(const u32x4*)pk;
      }
    }
  }
  __syncthreads();

  // stage-1: in-block LN stats from the bf16 tile (4 threads per pixel)
  if (!useg) {
    int pp = t >> 2, sub = t & 3;
    float s1 = 0.f, s2 = 0.f;
#pragma unroll
    for (int b2 = 0; b2 < 4; ++b2) {
      int c8 = (sub * 4 + b2) * 8;
      int c8s = c8 ^ ((pp & 7) << 3);
      bf16x8 v = *(const bf16x8*)&Bs[pp * 128 + c8s];
#pragma unroll
      for (int q = 0; q < 8; ++q) {
        float f = bf2f((unsigned short)v[q]);
        s1 += f; s2 += f * f;
      }
    }
    s1 += __shfl_xor(s1, 1); s2 += __shfl_xor(s2, 1);
    s1 += __shfl_xor(s1, 2); s2 += __shfl_xor(s2, 2);
    if (sub == 0) {
      float m = s1 * (1.f / 128.f);
      muL[pp] = m;
      rsL[pp] = rsqrtf(s2 * (1.f / 128.f) - m * m + 1e-5f);
    }
    __syncthreads();
  }

  // MFMA: wave w covers rows m0+32w..+32 (2 frags) x 64 px (4 frags)
  f32x4 acc[2][4];
#pragma unroll
  for (int i = 0; i < 2; ++i)
#pragma unroll
    for (int j = 0; j < 4; ++j) acc[i][j] = (f32x4){0.f, 0.f, 0.f, 0.f};
#pragma unroll
  for (int ks = 0; ks < 4; ++ks) {
    int colx = (ks * 32 + lg * 8) ^ ((lr & 7) << 3);
    bf16x8 bfr[4];
#pragma unroll
    for (int j = 0; j < 4; ++j)
      bfr[j] = *(const bf16x8*)&Bs[(16 * j + lr) * 128 + colx];
#pragma unroll
    for (int i = 0; i < 2; ++i) {
      bf16x8 afr = *(const bf16x8*)&As[(32 * w + 16 * i + lr) * 128 + colx];
#pragma unroll
      for (int j = 0; j < 4; ++j)
        acc[i][j] = __builtin_amdgcn_mfma_f32_16x16x32_bf16(afr, bfr[j], acc[i][j], 0, 0, 0);
    }
  }

  // epilogue
  float rsv[4], muv[4];
#pragma unroll
  for (int j = 0; j < 4; ++j) {
    int nl = 16 * j + lr;
    if (useg) {
      rsv[j] = rs[(size_t)bg * NN + n0 + nl];
      muv[j] = mu[(size_t)bg * NN + n0 + nl];
    } else {
      rsv[j] = rsL[nl];
      muv[j] = muL[nl];
    }
  }
#pragma unroll
  for (int i = 0; i < 2; ++i) {
    int ob = m0 + 32 * w + 16 * i + lg * 4;
    float sv[4], bv[4];
#pragma unroll
    for (int r2 = 0; r2 < 4; ++r2) { sv[r2] = Svec[ob + r2]; bv[r2] = bias2[ob + r2]; }
#pragma unroll
    for (int j = 0; j < 4; ++j) {
      int n = n0 + 16 * j + lr;
      unsigned short* op = out + (size_t)bz * O3N + n;
#pragma unroll
      for (int r2 = 0; r2 < 4; ++r2)
        op[(size_t)(ob + r2) * NN] = f2bf(rsv[j] * (acc[i][j][r2] - muv[j] * sv[r2]) + bv[r2]);
    }
  }
}

// ---- 3x3 depthwise conv, bf16 in/out, padded-LDS (halo-only zero), fused stage-1 reductions ----
__global__ __launch_bounds__(1024) void k_dwc(unsigned short* __restrict__ buf,
                                              const float* __restrict__ dww,
                                              const float* __restrict__ dwb,
                                              float* __restrict__ qm,
                                              float* __restrict__ km,
                                              int b0, int stage) {
  __shared__ unsigned short pl[130 * 144];         // rows -1..128, cols -8..135 (72 u32/row)
  __shared__ float red[32 * 128];
  int o = blockIdx.x, bz = blockIdx.y, bg = b0 + bz;
  int t = threadIdx.x;
  unsigned short* base = buf + (size_t)bz * O3N + (size_t)o * NN;
  unsigned* pl32 = (unsigned*)pl;

  for (int i = t; i < 1168; i += 1024) {
    int idx;
    if (i < 72) idx = i;
    else if (i < 144) idx = 129 * 72 + (i - 72);
    else { int j = i - 144; int row = (j >> 3) + 1; int s = j & 7;
           idx = row * 72 + (s < 4 ? s : 64 + s); }
    pl32[idx] = 0u;
  }
  __syncthreads();
#pragma unroll
  for (int r = 0; r < 2; ++r) {
    int idx = r * 1024 + t;
    int row = idx >> 4, c8 = (idx & 15) * 8;
    *(u32x4*)&pl[(row + 1) * 144 + 8 + c8] = *(const u32x4*)&base[row * 128 + c8];
  }
  __syncthreads();

  const float* wg = dww + o * 9;
  float w00 = wg[0], w01 = wg[1], w02 = wg[2];
  float w10 = wg[3], w11 = wg[4], w12 = wg[5];
  float w20 = wg[6], w21 = wg[7], w22 = wg[8];
  float bias = dwb[o];
  int mode = (stage == 0) ? (o < 128 ? 1 : (o < 256 ? 2 : 0)) : 0;
  int hh0 = t >> 5, w0 = (t & 31) * 4;
  float csum[4] = {0.f, 0.f, 0.f, 0.f};
  float cmax[4] = {-1e30f, -1e30f, -1e30f, -1e30f};

#pragma unroll
  for (int g = 0; g < 4; ++g) {
    int h = g * 32 + hh0;
    float a0 = bias, a1 = bias, a2 = bias, a3 = bias;
#pragma unroll
    for (int dr = 0; dr < 3; ++dr) {
      const unsigned short* rp = &pl[(h + dr) * 144];
      us4 cA = *(const us4*)&rp[w0 + 4];
      us4 cB = *(const us4*)&rp[w0 + 8];
      us4 cC = *(const us4*)&rp[w0 + 12];
      float f0 = bf2f(cA[3]), f1 = bf2f(cB[0]), f2 = bf2f(cB[1]);
      float f3 = bf2f(cB[2]), f4 = bf2f(cB[3]), f5 = bf2f(cC[0]);
      float wr0 = (dr == 0) ? w00 : (dr == 1 ? w10 : w20);
      float wr1 = (dr == 0) ? w01 : (dr == 1 ? w11 : w21);
      float wr2 = (dr == 0) ? w02 : (dr == 1 ? w12 : w22);
      a0 += f0 * wr0 + f1 * wr1 + f2 * wr2;
      a1 += f1 * wr0 + f2 * wr1 + f3 * wr2;
      a2 += f2 * wr0 + f3 * wr1 + f4 * wr2;
      a3 += f3 * wr0 + f4 * wr1 + f5 * wr2;
    }
    if (mode == 0) {
      us4 ov;
      ov[0] = f2bf(a0); ov[1] = f2bf(a1); ov[2] = f2bf(a2); ov[3] = f2bf(a3);
      *(us4*)&base[g * 4096 + t * 4] = ov;
    } else if (mode == 1) {
      csum[0] += a0; csum[1] += a1; csum[2] += a2; csum[3] += a3;
    } else {
      cmax[0] = fmaxf(cmax[0], a0); cmax[1] = fmaxf(cmax[1], a1);
      cmax[2] = fmaxf(cmax[2], a2); cmax[3] = fmaxf(cmax[3], a3);
    }
  }

  if (mode) {
    int j = t >> 5;
#pragma unroll
    for (int dx = 0; dx < 4; ++dx)
      red[j * 128 + w0 + dx] = (mode == 1) ? csum[dx] : cmax[dx];
    __syncthreads();
    if (t < 128) {
      float v = red[t];
      if (mode == 1) {
        for (int jj = 1; jj < 32; ++jj) v += red[jj * 128 + t];
        qm[(size_t)bg * NN + o * 128 + t] = v * (1.f / 128.f);
      } else {
        for (int jj = 1; jj < 32; ++jj) v = fmaxf(v, red[jj * 128 + t]);
        km[(size_t)bg * NN + (o - 128) * 128 + t] = v;
      }
    }
  }
}

// ---- stage-2 reductions: mean over channels of bf16 q,k planes -> [b, h, w] ----
__global__ __launch_bounds__(256) void k_reduce2(const unsigned short* __restrict__ qkv,
                                                 float* __restrict__ qm, float* __restrict__ km,
                                                 int b0) {
  int bz = blockIdx.y;
  int n = blockIdx.x * 256 + threadIdx.x;
  const unsigned short* base = qkv + (size_t)bz * O3N + n;
  float sq = 0.f, sk = 0.f;
#pragma unroll 4
  for (int c = 0; c < 128; ++c) {
    sq += bf2f(base[(size_t)c * NN]);
    sk += bf2f(base[(size_t)(c + 128) * NN]);
  }
  size_t off = (size_t)(b0 + bz) * NN + n;
  qm[off] = sq * (1.f / 128.f);
  km[off] = sk * (1.f / 128.f);
}

// ---- l2-normalize rows of length 128 in place ----
__global__ void k_norm2(float* __restrict__ qm, float* __restrict__ km, int row0) {
  float* buf = blockIdx.y ? km : qm;
  int r = row0 + blockIdx.x, t = threadIdx.x;   // 64 threads
  float* p = buf + (size_t)r * 128;
  float v0 = p[t], v1 = p[t + 64];
  float s = wave_sum(v0 * v0 + v1 * v1);
  float sc = 1.f / fmaxf(sqrtf(s), 1e-12f);
  p[t] = v0 * sc;
  p[t + 64] = v1 * sc;
}

// ---- attn1: scores over c; writes attnT[v][w] bf16 ----
__global__ void k_attn1(const float* __restrict__ qm, const float* __restrict__ km,
                        const float* __restrict__ temp, unsigned short* __restrict__ attnT,
                        int b0) {
  int bg = b0 + blockIdx.y;
  int i = blockIdx.x, t = threadIdx.x;          // i = w (query), t = v (key)
  const float* qb = qm + (size_t)bg * NN;
  const float* kb = km + (size_t)bg * NN;
  __shared__ float qcol[128];
  __shared__ float wred[2];
  qcol[t] = qb[t * 128 + i];
  __syncthreads();
  float s = 0.f;
#pragma unroll 4
  for (int k = 0; k < 128; ++k) s += qcol[k] * kb[k * 128 + t];
  s *= temp[0];
  int wid = t >> 6, lane = t & 63;
  float mx = wave_max(s);
  if (lane == 0) wred[wid] = mx;
  __syncthreads();
  mx = fmaxf(wred[0], wred[1]);
  float pv = __expf(s - mx);
  __syncthreads();
  float sm = wave_sum(pv);
  if (lane == 0) wred[wid] = sm;
  __syncthreads();
  float denom = wred[0] + wred[1];
  attnT[(size_t)bg * NN + (size_t)t * 128 + i] = f2bf(pv / denom);
}

// ---- attn2: scores over w; writes attnT[g][h] bf16 ----
__global__ void k_attn2(const float* __restrict__ qm, const float* __restrict__ km,
                        const float* __restrict__ temp, unsigned short* __restrict__ attnT,
                        int b0) {
  int bg = b0 + blockIdx.y;
  int i = blockIdx.x, t = threadIdx.x;          // i = h, t = g
  const float* qb = qm + (size_t)bg * NN + i * 128;
  const float* kb = km + (size_t)bg * NN + (size_t)t * 128;
  __shared__ float qrow[128];
  __shared__ float wred[2];
  qrow[t] = qb[t];
  __syncthreads();
  float s = 0.f;
#pragma unroll 4
  for (int w = 0; w < 128; ++w) s += qrow[w] * kb[w];
  s *= temp[0];
  int wid = t >> 6, lane = t & 63;
  float mx = wave_max(s);
  if (lane == 0) wred[wid] = mx;
  __syncthreads();
  mx = fmaxf(wred[0], wred[1]);
  float pv = __expf(s - mx);
  __syncthreads();
  float sm = wave_sum(pv);
  if (lane == 0) wred[wid] = sm;
  __syncthreads();
  float denom = wred[0] + wred[1];
  attnT[(size_t)bg * NN + (size_t)t * 128 + i] = f2bf(pv / denom);
}

// ---- FUSED stage-1 apply+proj+stats: one block per h-row. ----
__global__ __launch_bounds__(256) void k_ap1(const unsigned short* __restrict__ buf,
                                             const unsigned short* __restrict__ attnT,
                                             const unsigned short* __restrict__ Ap,
                                             const float* __restrict__ pb,
                                             const float* __restrict__ x,
                                             unsigned short* __restrict__ out1,
                                             float* __restrict__ mu, float* __restrict__ rs,
                                             int b0) {
  __shared__ __attribute__((aligned(16))) unsigned short S[32768];   // 64 KB, two 32KB tiles
  unsigned short* TA = S;            // GEMM1 A (v1 rows), then tmpT [v][c]
  unsigned short* TB = S + 16384;    // GEMM1 B (attnT), then Ap [o][c]
  int h = blockIdx.x, bz = blockIdx.z, bg = b0 + bz;
  int t = threadIdx.x, wv = t >> 6, l = t & 63, lr = l & 15, lg = l >> 4;

  // stage A1 (v1 rows m=c*128+h) and B1 (attnT), XOR-swizzled 8-col granules
  {
    const unsigned short* vbase = buf + (size_t)bz * O3N + (size_t)256 * NN;
    const unsigned short* abase = attnT + (size_t)bg * NN;
#pragma unroll
    for (int r = 0; r < 8; ++r) {
      int idx = r * 256 + t;
      int row = idx >> 4, c8 = (idx & 15) * 8;
      int c8s = c8 ^ ((row & 7) << 3);
      *(u32x4*)&TA[row * 128 + c8s] = *(const u32x4*)&vbase[((size_t)row * 128 + h) * 128 + c8];
      *(u32x4*)&TB[row * 128 + c8s] = *(const u32x4*)&abase[row * 128 + c8];
    }
  }
  __syncthreads();

  // GEMM1: rows c = 32wv+16i+..., cols v (8 j-frags), K = w
  f32x4 acc[2][8];
#pragma unroll
  for (int i = 0; i < 2; ++i)
#pragma unroll
    for (int j = 0; j < 8; ++j) acc[i][j] = (f32x4){0.f, 0.f, 0.f, 0.f};
#pragma unroll
  for (int ks = 0; ks < 4; ++ks) {
    int colx = (ks * 32 + lg * 8) ^ ((lr & 7) << 3);
    bf16x8 bfr[8];
#pragma unroll
    for (int j = 0; j < 8; ++j)
      bfr[j] = *(const bf16x8*)&TB[(16 * j + lr) * 128 + colx];
#pragma unroll
    for (int i = 0; i < 2; ++i) {
      bf16x8 afr = *(const bf16x8*)&TA[(32 * wv + 16 * i + lr) * 128 + colx];
#pragma unroll
      for (int j = 0; j < 8; ++j)
        acc[i][j] = __builtin_amdgcn_mfma_f32_16x16x32_bf16(afr, bfr[j], acc[i][j], 0, 0, 0);
    }
  }
  __syncthreads();   // TA/TB dead

  // stage Ap into TB via async direct-to-LDS (pre-swizzled source, linear copy)
#pragma unroll
  for (int r = 0; r < 8; ++r) {
    int v = r * 256 + t;
    gl_lds16(&Ap[(size_t)v * 8], &TB[(size_t)(r * 256 + (t & 192)) * 8]);
  }
  // write tmpT [v][c] into TA
#pragma unroll
  for (int i = 0; i < 2; ++i) {
    int c0 = 32 * wv + 16 * i + lg * 4;
#pragma unroll
    for (int j = 0; j < 8; ++j) {
      int v = 16 * j + lr;
      us4 ov;
#pragma unroll
      for (int r2 = 0; r2 < 4; ++r2) ov[r2] = f2bf(acc[i][j][r2]);
      *(us4*)&TA[v * 128 + (c0 ^ ((v & 7) << 3))] = ov;
    }
  }
  __syncthreads();

  // GEMM2: rows o, cols v, K = c
#pragma unroll
  for (int i = 0; i < 2; ++i)
#pragma unroll
    for (int j = 0; j < 8; ++j) acc[i][j] = (f32x4){0.f, 0.f, 0.f, 0.f};
#pragma unroll
  for (int ks = 0; ks < 4; ++ks) {
    int colx = (ks * 32 + lg * 8) ^ ((lr & 7) << 3);
    bf16x8 bfr[8];
#pragma unroll
    for (int j = 0; j < 8; ++j)
      bfr[j] = *(const bf16x8*)&TA[(16 * j + lr) * 128 + colx];
#pragma unroll
    for (int i = 0; i < 2; ++i) {
      bf16x8 afr = *(const bf16x8*)&TB[(32 * wv + 16 * i + lr) * 128 + colx];
#pragma unroll
      for (int j = 0; j < 8; ++j)
        acc[i][j] = __builtin_amdgcn_mfma_f32_16x16x32_bf16(afr, bfr[j], acc[i][j], 0, 0, 0);
    }
  }

  // epilogue: +bias +residual(x fp32), write out1 bf16, accumulate stats
  float s1p[8], s2p[8];
#pragma unroll
  for (int j = 0; j < 8; ++j) { s1p[j] = 0.f; s2p[j] = 0.f; }
#pragma unroll
  for (int i = 0; i < 2; ++i) {
    int o0 = 32 * wv + 16 * i + lg * 4;
    float bv[4];
#pragma unroll
    for (int r2 = 0; r2 < 4; ++r2) bv[r2] = pb[o0 + r2];
#pragma unroll
    for (int j = 0; j < 8; ++j) {
      int n = h * 128 + 16 * j + lr;
#pragma unroll
      for (int r2 = 0; r2 < 4; ++r2) {
        size_t off = (size_t)bg * CN + (size_t)(o0 + r2) * NN + n;
        float val = acc[i][j][r2] + bv[r2] + x[off];
        out1[off] = f2bf(val);
        s1p[j] += val;
        s2p[j] += val * val;
      }
    }
  }
  __syncthreads();   // TA/TB dead -> overlay reduction arrays
  float* red1 = (float*)S;              // [128][17]
  float* red2 = red1 + 128 * 17;
#pragma unroll
  for (int j = 0; j < 8; ++j) {
    red1[(16 * j + lr) * 17 + (wv * 4 + lg)] = s1p[j];
    red2[(16 * j + lr) * 17 + (wv * 4 + lg)] = s2p[j];
  }
  __syncthreads();
  if (t < 128) {
    float s1 = 0.f, s2 = 0.f;
#pragma unroll
    for (int kk = 0; kk < 16; ++kk) { s1 += red1[t * 17 + kk]; s2 += red2[t * 17 + kk]; }
    float m = s1 * (1.f / 128.f);
    float var = s2 * (1.f / 128.f) - m * m;
    mu[(size_t)bg * NN + h * 128 + t] = m;
    rs[(size_t)bg * NN + h * 128 + t] = rsqrtf(var + 1e-5f);
  }
}

// ---- apply2 (MFMA): tmp[c][g*128+w] = sum_h attnT[g][h] * v2plane[h][w] ----
__global__ __launch_bounds__(256) void k_apply2_mfma(unsigned short* __restrict__ buf,
                                                     const unsigned short* __restrict__ attnT,
                                                     int b0) {
  __shared__ unsigned short At[128 * 136];
  __shared__ unsigned short Bt[128 * 136];       // v2 plane transposed [w][h]
  int bz = blockIdx.z, bg = b0 + bz, c = blockIdx.x;
  int t = threadIdx.x, w = t >> 6, l = t & 63, lr = l & 15, lg = l >> 4;
  const unsigned short* vsrc = buf + (size_t)bz * O3N + (size_t)(256 + c) * NN;
  const unsigned short* asrc = attnT + (size_t)bg * NN;
#pragma unroll
  for (int r = 0; r < 8; ++r) {
    int idx = r * 256 + t;
    int row = idx >> 4, c8 = (idx & 15) * 8;
    *(u32x4*)&At[row * 136 + c8] = *(const u32x4*)&asrc[row * 128 + c8];
    us4 lo = *(const us4*)&vsrc[row * 128 + c8];
    us4 hi = *(const us4*)&vsrc[row * 128 + c8 + 4];
#pragma unroll
    for (int q = 0; q < 4; ++q) {
      Bt[(c8 + q) * 136 + row] = lo[q];
      Bt[(c8 + 4 + q) * 136 + row] = hi[q];
    }
  }
  __syncthreads();
  f32x4 acc[2][8];
#pragma unroll
  for (int i = 0; i < 2; ++i)
#pragma unroll
    for (int j = 0; j < 8; ++j) acc[i][j] = (f32x4){0.f, 0.f, 0.f, 0.f};
#pragma unroll
  for (int ks = 0; ks < 4; ++ks) {
    bf16x8 bfr[8];
#pragma unroll
    for (int j = 0; j < 8; ++j)
      bfr[j] = *(const bf16x8*)&Bt[(16 * j + lr) * 136 + ks * 32 + lg * 8];
#pragma unroll
    for (int i = 0; i < 2; ++i) {
      bf16x8 afr = *(const bf16x8*)&At[(32 * w + 16 * i + lr) * 136 + ks * 32 + lg * 8];
#pragma unroll
      for (int j = 0; j < 8; ++j)
        acc[i][j] = __builtin_amdgcn_mfma_f32_16x16x32_bf16(afr, bfr[j], acc[i][j], 0, 0, 0);
    }
  }
  unsigned short* ob = buf + (size_t)bz * O3N + (size_t)c * NN;  // q-region plane c
#pragma unroll
  for (int i = 0; i < 2; ++i)
#pragma unroll
    for (int j = 0; j < 8; ++j)
#pragma unroll
      for (int r2 = 0; r2 < 4; ++r2) {
        int g = 32 * w + 16 * i + lg * 4 + r2;
        int n = 16 * j + lr;
        ob[(size_t)g * 128 + n] = f2bf(acc[i][j][r2]);
      }
}

// ---- proj (MFMA) + residual (bf16 res, fp32 dst); A via global_load_lds ----
__global__ __launch_bounds__(256) void k_proj_mfma(
    const unsigned short* __restrict__ tin, const unsigned short* __restrict__ Ap,
    const float* __restrict__ pb, const unsigned short* __restrict__ res,
    float* __restrict__ dst, int b0) {
  __shared__ unsigned short Al[128 * 128];         // 32 KB, linear (pre-swizzled content)
  __shared__ unsigned short Bs2[64 * 128];
  int bz = blockIdx.z, bg = b0 + bz;
  int n0 = blockIdx.x * 64;
  int t = threadIdx.x, w = t >> 6, l = t & 63, lr = l & 15, lg = l >> 4;
  const unsigned short* tb = tin + (size_t)bz * O3N + n0;

#pragma unroll
  for (int r = 0; r < 8; ++r) {
    int v = r * 256 + t;
    gl_lds16(&Ap[(size_t)v * 8], &Al[(size_t)(r * 256 + (t & 192)) * 8]);
  }
  {
    int n = t & 63, cb = t >> 6;
    unsigned short vr[32];
#pragma unroll
    for (int g = 0; g < 4; ++g)
#pragma unroll
      for (int q = 0; q < 8; ++q)
        vr[g * 8 + q] = tb[(size_t)((cb * 4 + g) * 8 + q) * NN + n];
#pragma unroll
    for (int g = 0; g < 4; ++g) {
      int c8 = (cb * 4 + g) * 8;
      unsigned pk[4];
#pragma unroll
      for (int q = 0; q < 4; ++q)
        pk[q] = (unsigned)vr[g * 8 + 2 * q] | ((unsigned)vr[g * 8 + 2 * q + 1] << 16);
      int c8s = c8 ^ ((n & 7) << 3);
      *(u32x4*)&Bs2[n * 128 + c8s] = *(const u32x4*)pk;
    }
  }
  __syncthreads();

  f32x4 acc[2][4];
#pragma unroll
  for (int i = 0; i < 2; ++i)
#pragma unroll
    for (int j = 0; j < 4; ++j) acc[i][j] = (f32x4){0.f, 0.f, 0.f, 0.f};

#pragma unroll
  for (int ks = 0; ks < 4; ++ks) {
    int colx = (ks * 32 + lg * 8) ^ ((lr & 7) << 3);
    bf16x8 bfr[4];
#pragma unroll
    for (int j = 0; j < 4; ++j)
      bfr[j] = *(const bf16x8*)&Bs2[(16 * j + lr) * 128 + colx];
#pragma unroll
    for (int i = 0; i < 2; ++i) {
      bf16x8 afr = *(const bf16x8*)&Al[(32 * w + 16 * i + lr) * 128 + colx];
#pragma unroll
      for (int j = 0; j < 4; ++j)
        acc[i][j] = __builtin_amdgcn_mfma_f32_16x16x32_bf16(afr, bfr[j], acc[i][j], 0, 0, 0);
    }
  }

#pragma unroll
  for (int i = 0; i < 2; ++i) {
    int ob = 32 * w + 16 * i + lg * 4;
    float bv[4];
#pragma unroll
    for (int r2 = 0; r2 < 4; ++r2) bv[r2] = pb[ob + r2];
#pragma unroll
    for (int j = 0; j < 4; ++j) {
      int n = n0 + 16 * j + lr;
#pragma unroll
      for (int r2 = 0; r2 < 4; ++r2) {
        size_t off = (size_t)bg * CN + (size_t)(ob + r2) * NN + n;
        dst[off] = acc[i][j][r2] + bv[r2] + bf2f(res[off]);
      }
    }
  }
}

extern "C" void kernel_launch(void* const* d_in, const int* in_sizes, int n_in,
                              void* d_out, int out_size, void* d_ws, size_t ws_size,
                              hipStream_t stream) {
  (void)in_sizes; (void)n_in; (void)out_size;
  const float* x     = (const float*)d_in[0];
  const float* lnw   = (const float*)d_in[1];
  const float* lnb   = (const float*)d_in[2];
  const float* qkvw  = (const float*)d_in[3];
  const float* qkvb  = (const float*)d_in[4];
  const float* dww   = (const float*)d_in[5];
  const float* dwb   = (const float*)d_in[6];
  const float* projw = (const float*)d_in[7];
  const float* projb = (const float*)d_in[8];
  const float* temp1 = (const float*)d_in[9];
  const float* temp2 = (const float*)d_in[10];
  float* out = (float*)d_out;
  float* ws = (float*)d_ws;

  // floats: convbuf bf16 (nb*O3N/2) + out1 bf16 (8*CN/2 = 4*CN) + mu,rs,qm,km + attnT + consts
  auto needBytes = [&](int nb) {
    return ((size_t)nb * (O3N / 2) + 4ull * CN + 4ull * 131072 + 65536 + 768 + 24576 + 8192) * 4;
  };
  int NB = 8;
  while (NB > 1 && ws_size < needBytes(NB)) NB >>= 1;
  if (ws_size < needBytes(1)) return;

  unsigned short* convbuf = (unsigned short*)ws;
  unsigned short* out1 = (unsigned short*)(ws + (size_t)NB * (O3N / 2));
  float* mu = ws + (size_t)NB * (O3N / 2) + 4ull * CN;
  float* rs = mu + 131072;
  float* qm = rs + 131072;
  float* km = qm + 131072;
  unsigned short* attnT = (unsigned short*)(km + 131072);
  float* Svec  = (float*)(attnT + 8ull * NN);
  float* bias2 = Svec + 384;
  unsigned short* Aq = (unsigned short*)(bias2 + 384);
  unsigned short* Ap = Aq + 49152;

  k_prep<<<512, 64, 0, stream>>>(qkvw, qkvb, lnw, lnb, projw, Aq, Ap, Svec, bias2);

  // ---- stage 1 ----
  for (int b0 = 0; b0 < 8; b0 += NB) {
    k_qkv_mfma<<<dim3(768, 1, NB), 256, 0, stream>>>(x, mu, rs, Aq, Svec, bias2, convbuf,
                                                     b0, 0, 0);
    k_dwc<<<dim3(384, NB), 1024, 0, stream>>>(convbuf, dww, dwb, qm, km, b0, 0);
    k_norm2<<<dim3(NB * 128, 2), 64, 0, stream>>>(qm, km, b0 * 128);
    k_attn1<<<dim3(128, NB), 128, 0, stream>>>(qm, km, temp1, attnT, b0);
    k_ap1<<<dim3(128, 1, NB), 256, 0, stream>>>(convbuf, attnT, Ap, projb, x, out1, mu, rs, b0);
  }
  // ---- stage 2 ----
  for (int b0 = 0; b0 < 8; b0 += NB) {
    k_qkv_mfma<<<dim3(768, 1, NB), 256, 0, stream>>>(out1, mu, rs, Aq, Svec, bias2, convbuf,
                                                     b0, 1, 1);
    k_dwc<<<dim3(384, NB), 1024, 0, stream>>>(convbuf, dww, dwb, qm, km, b0, 1);
    k_reduce2<<<dim3(64, NB), 256, 0, stream>>>(convbuf, qm, km, b0);
    k_norm2<<<dim3(NB * 128, 2), 64, 0, stream>>>(qm, km, b0 * 128);
    k_attn2<<<dim3(128, NB), 128, 0, stream>>>(qm, km, temp2, attnT, b0);
    k_apply2_mfma<<<dim3(128, 1, NB), 256, 0, stream>>>(convbuf, attnT, b0);
    k_proj_mfma<<<dim3(256, 1, NB), 256, 0, stream>>>(convbuf, Ap, projb, out1, out, b0);
  }
}